// Round 1
// baseline (4789.149 us; speedup 1.0000x reference)
//
#include <hip/hip_runtime.h>
#include <hip/hip_bf16.h>
#include <cstdint>
#include <cstddef>

#define NNODES 100000
#define NEDGES 1600000
#define EMBD 128
#define NLAYER 5
#define XDIM 178
#define EDIM 18
#define BNEPS 1e-5f

static __device__ __forceinline__ float leakyf(float v){ return v > 0.f ? v : 0.1f*v; }
static __device__ __forceinline__ float toF(float v){ return v; }
static __device__ __forceinline__ float toF(__hip_bfloat16 v){ return __bfloat162float(v); }

// ---------------- CSR build ----------------
__global__ __launch_bounds__(256) void k_hist(const int* __restrict__ dst, int* __restrict__ cnt){
  int e = blockIdx.x*256 + threadIdx.x;
  if (e < NEDGES) atomicAdd(&cnt[dst[e]], 1);
}

__global__ __launch_bounds__(256) void k_scan1(const int* __restrict__ cnt, int* __restrict__ rowptr,
                                               int* __restrict__ bsum){
  __shared__ int s[256];
  int t = threadIdx.x, i = blockIdx.x*256 + t;
  int v = (i < NNODES) ? cnt[i] : 0;
  s[t] = v; __syncthreads();
  for (int off=1; off<256; off<<=1){
    int x = (t>=off) ? s[t-off] : 0; __syncthreads();
    s[t] += x; __syncthreads();
  }
  if (i < NNODES) rowptr[i+1] = s[t];
  if (t == 255) bsum[blockIdx.x] = s[t];
}

__global__ __launch_bounds__(512) void k_scan2(const int* __restrict__ bsum, int* __restrict__ boff, int nb){
  __shared__ int s[512];
  int t = threadIdx.x;
  int v = (t < nb) ? bsum[t] : 0;
  s[t] = v; __syncthreads();
  for (int off=1; off<512; off<<=1){
    int x = (t>=off) ? s[t-off] : 0; __syncthreads();
    s[t] += x; __syncthreads();
  }
  if (t < nb) boff[t] = s[t] - v;
}

__global__ __launch_bounds__(256) void k_scan3(int* __restrict__ rowptr, const int* __restrict__ boff){
  int i = blockIdx.x*256 + threadIdx.x;
  if (i < NNODES) rowptr[i+1] += boff[i>>8];
  if (i == 0) rowptr[0] = 0;
}

__global__ __launch_bounds__(256) void k_curcopy(const int* __restrict__ rowptr, int* __restrict__ cursor){
  int i = blockIdx.x*256 + threadIdx.x;
  if (i < NNODES) cursor[i] = rowptr[i];
}

__global__ __launch_bounds__(256) void k_fill(const int* __restrict__ src, const int* __restrict__ dst,
                                              const float* __restrict__ ea, int* __restrict__ cursor,
                                              int* __restrict__ perm, int* __restrict__ srcp,
                                              float* __restrict__ eap){
  int e = blockIdx.x*256 + threadIdx.x;
  if (e >= NEDGES) return;
  int pos = atomicAdd(&cursor[dst[e]], 1);
  perm[pos] = e;
  srcp[pos] = src[e];
  if (eap){
    const float* a = ea + (size_t)e*EDIM;
    float* o = eap + (size_t)pos*EDIM;
    #pragma unroll
    for (int k=0;k<EDIM;++k) o[k] = a[k];
  }
}

// self_e[l] = leaky(eb1[l]) @ ew2[l] + eb2[l]
__global__ __launch_bounds__(128) void k_selfe(const float* __restrict__ eb1, const float* __restrict__ ew2,
                                               const float* __restrict__ eb2, float* __restrict__ selfe){
  int l = blockIdx.x, c = threadIdx.x;
  const float* b1 = eb1 + l*EMBD;
  const float* w2 = ew2 + (size_t)l*EMBD*EMBD;
  float acc = eb2[l*EMBD + c];
  for (int j=0;j<EMBD;++j) acc += leakyf(b1[j]) * w2[j*EMBD + c];
  selfe[l*EMBD + c] = acc;
}

// ------------- per-layer edge + aggregate (one wave per dst node) -------------
__global__ __launch_bounds__(256) void k_edge(
    const float* __restrict__ h, const int* __restrict__ rowptr,
    const int* __restrict__ perm, const int* __restrict__ srcp,
    const float* __restrict__ edge_attr, const float* __restrict__ eaperm,
    const float* __restrict__ ew1l, const float* __restrict__ eb1l,
    const float* __restrict__ eb2l, const float* __restrict__ selfel,
    float* __restrict__ S1, float* __restrict__ base)
{
  __shared__ float w1s[EDIM*EMBD];
  __shared__ float b1s[EMBD];
  int tid = threadIdx.x;
  for (int i = tid; i < EDIM*EMBD; i += 256) w1s[i] = ew1l[i];
  if (tid < EMBD) b1s[tid] = eb1l[tid];
  __syncthreads();
  int lane = tid & 63;
  int node = blockIdx.x*4 + (tid >> 6);
  if (node >= NNODES) return;
  int rs = rowptr[node], re = rowptr[node+1];
  int c0 = lane*2;
  float s1x=0.f, s1y=0.f, bx=0.f, by=0.f;
  for (int i = rs; i < re; ++i){
    int s = __builtin_amdgcn_readfirstlane(srcp[i]);
    const float* ea;
    if (eaperm){
      ea = eaperm + (size_t)__builtin_amdgcn_readfirstlane(i)*EDIM;
    } else {
      ea = edge_attr + (size_t)__builtin_amdgcn_readfirstlane(perm[i])*EDIM;
    }
    float2 hs = *(const float2*)(h + (size_t)s*EMBD + c0);
    bx += hs.x; by += hs.y;
    float d0 = b1s[c0], d1 = b1s[c0+1];
    #pragma unroll
    for (int k=0;k<EDIM;++k){
      float av = ea[k];
      d0 += av * w1s[k*EMBD + c0];
      d1 += av * w1s[k*EMBD + c0 + 1];
    }
    s1x += leakyf(d0); s1y += leakyf(d1);
  }
  float deg = (float)(re - rs);
  float2 hv = *(const float2*)(h + (size_t)node*EMBD + c0);
  *(float2*)(S1 + (size_t)node*EMBD + c0) = make_float2(s1x, s1y);
  float bvx = bx + hv.x + selfel[c0]   + deg*eb2l[c0];
  float bvy = by + hv.y + selfel[c0+1] + deg*eb2l[c0+1];
  *(float2*)(base + (size_t)node*EMBD + c0) = make_float2(bvx, bvy);
}

// ------------- generic tiled GEMM: C[M,ldc-chunk] = act(A[M,K] @ B[K,ldb] + bias) (+addsrc) -------------
// ACT: 0 none, 1 leaky(0.1), 2 relu.  Tile: 64x128, BK=32, 256 threads, thread tile 4x8.
template<typename TA, int ACT, bool ADD, bool STATS, bool OBF16>
__global__ __launch_bounds__(256) void k_gemm(
    const TA* __restrict__ A, int M, int K,
    const float* __restrict__ B, int ldb,
    const float* __restrict__ bias,
    const float* __restrict__ addsrc,
    float* __restrict__ Cf, __hip_bfloat16* __restrict__ Cb, int ldc,
    float* __restrict__ stats)
{
  constexpr int BM=64, BN=128, BK=32;
  __shared__ float As[BM][BK+1];
  __shared__ float Bs[BK][BN+4];
  __shared__ float ssum[BN], ssq[BN];
  int tid = threadIdx.x;
  int row0 = blockIdx.x*BM;
  int colOff = blockIdx.y*BN;
  int tx = tid & 15, ty = tid >> 4;
  int ty4 = ty*4, tx8 = tx*8;
  float acc[4][8];
  #pragma unroll
  for (int j=0;j<4;++j)
    #pragma unroll
    for (int i=0;i<8;++i) acc[j][i] = 0.f;

  for (int k0=0; k0<K; k0+=BK){
    int kc = (K - k0 < BK) ? (K - k0) : BK;
    #pragma unroll
    for (int u=0;u<8;++u){
      int idx = tid + u*256, m = idx>>5, k = idx&31;
      int gr = row0+m, gk = k0+k;
      float v = 0.f;
      if (gr < M && gk < K) v = toF(A[(size_t)gr*K + gk]);
      As[m][k] = v;
    }
    #pragma unroll
    for (int u=0;u<4;++u){
      int idx = tid + u*256, r = idx>>5, c4 = idx&31;
      float4 v = make_float4(0.f,0.f,0.f,0.f);
      if (r < kc) v = *(const float4*)(B + (size_t)(k0+r)*ldb + colOff + c4*4);
      *(float4*)&Bs[r][c4*4] = v;
    }
    __syncthreads();
    auto step = [&](int kk){
      float ar[4];
      #pragma unroll
      for (int j=0;j<4;++j) ar[j] = As[ty4+j][kk];
      const float4* bp = (const float4*)&Bs[kk][tx8];
      float4 b0 = bp[0], b1v = bp[1];
      float br[8] = {b0.x,b0.y,b0.z,b0.w,b1v.x,b1v.y,b1v.z,b1v.w};
      #pragma unroll
      for (int j=0;j<4;++j)
        #pragma unroll
        for (int i=0;i<8;++i) acc[j][i] = fmaf(ar[j], br[i], acc[j][i]);
    };
    if (kc == BK){
      #pragma unroll
      for (int kk=0; kk<BK; ++kk) step(kk);
    } else {
      for (int kk=0; kk<kc; ++kk) step(kk);
    }
    __syncthreads();
  }

  float bv[8];
  #pragma unroll
  for (int i=0;i<8;++i) bv[i] = bias ? bias[colOff + tx8 + i] : 0.f;

  if (STATS){
    if (tid < BN){ ssum[tid] = 0.f; ssq[tid] = 0.f; }
    __syncthreads();
  }
  #pragma unroll
  for (int j=0;j<4;++j){
    int r = row0 + ty4 + j;
    if (r < M){
      #pragma unroll
      for (int i=0;i<8;++i){
        int c = colOff + tx8 + i;
        float v = acc[j][i] + bv[i];
        if (ADD) v += addsrc[(size_t)r*ldc + c];
        if (ACT == 1) v = leakyf(v);
        if (ACT == 2) v = fmaxf(v, 0.f);
        if (OBF16) Cb[(size_t)r*ldc + c] = __float2bfloat16(v);
        else       Cf[(size_t)r*ldc + c] = v;
        if (STATS){
          atomicAdd(&ssum[tx8+i], v);
          atomicAdd(&ssq[tx8+i], v*v);
        }
      }
    }
  }
  if (STATS){
    __syncthreads();
    if (tid < BN){
      atomicAdd(&stats[tid], ssum[tid]);
      atomicAdd(&stats[BN + tid], ssq[tid]);
    }
  }
}

// ------------- BatchNorm normalize (+optional relu) -------------
__global__ __launch_bounds__(256) void k_bn(const float* __restrict__ hh, const float* __restrict__ stats,
                                            const float* __restrict__ gamma, const float* __restrict__ beta,
                                            float* __restrict__ out, int dorelu){
  int idx = blockIdx.x*256 + threadIdx.x;          // over NNODES*EMBD/4 float4s
  if (idx >= NNODES*(EMBD/4)) return;
  int c0 = (idx & (EMBD/4 - 1)) * 4;
  float4 v = *(const float4*)(hh + (size_t)idx*4);
  float o[4] = {v.x, v.y, v.z, v.w};
  const float invN = 1.f / (float)NNODES;
  #pragma unroll
  for (int i=0;i<4;++i){
    int c = c0 + i;
    float mean = stats[c] * invN;
    float var  = stats[EMBD + c] * invN - mean*mean;
    float inv  = rsqrtf(fmaxf(var, 0.f) + BNEPS);
    float y = (o[i] - mean) * inv * gamma[c] + beta[c];
    if (dorelu) y = fmaxf(y, 0.f);
    o[i] = y;
  }
  *(float4*)(out + (size_t)idx*4) = make_float4(o[0],o[1],o[2],o[3]);
}

// ---------------- launcher ----------------
extern "C" void kernel_launch(void* const* d_in, const int* in_sizes, int n_in,
                              void* d_out, int out_size, void* d_ws, size_t ws_size,
                              hipStream_t stream)
{
  const float* x   = (const float*)d_in[0];
  const float* ea  = (const float*)d_in[1];
  const float* iw1 = (const float*)d_in[2];
  const float* ib1 = (const float*)d_in[3];
  const float* iw2 = (const float*)d_in[4];
  const float* ib2 = (const float*)d_in[5];
  const float* ew1 = (const float*)d_in[6];
  const float* eb1 = (const float*)d_in[7];
  const float* ew2 = (const float*)d_in[8];
  const float* eb2 = (const float*)d_in[9];
  const float* mw1 = (const float*)d_in[10];
  const float* mb1 = (const float*)d_in[11];
  const float* mw2 = (const float*)d_in[12];
  const float* mb2 = (const float*)d_in[13];
  const float* gamma = (const float*)d_in[14];
  const float* beta  = (const float*)d_in[15];
  const int* eidx = (const int*)d_in[16];
  const int* srcI = eidx;
  const int* dstI = eidx + NEDGES;

  char* p = (char*)d_ws;
  auto alloc = [&](size_t bytes)->char*{
    char* r = p; p += (bytes + 255) & ~(size_t)255; return r;
  };
  float* hbuf  = (float*)alloc((size_t)NNODES*EMBD*4);
  float* S1    = (float*)alloc((size_t)NNODES*EMBD*4);
  float* base  = (float*)alloc((size_t)NNODES*EMBD*4);
  __hip_bfloat16* tbuf = (__hip_bfloat16*)alloc((size_t)NNODES*2*EMBD*2);
  int* perm   = (int*)alloc((size_t)NEDGES*4);
  int* srcp   = (int*)alloc((size_t)NEDGES*4);
  int* rowptr = (int*)alloc((size_t)(NNODES+1)*4);
  int* cursor = (int*)alloc((size_t)NNODES*4);
  int* bsum   = (int*)alloc(4096);
  int* boff   = (int*)alloc(4096);
  float* selfe = (float*)alloc(NLAYER*EMBD*4);
  float* stats = (float*)alloc(2*EMBD*4);
  size_t used = (size_t)(p - (char*)d_ws);
  float* eaperm = nullptr;
  if (ws_size >= used + (size_t)NEDGES*EDIM*4 + 256)
    eaperm = (float*)alloc((size_t)NEDGES*EDIM*4);

  // ---- CSR build (per call; deterministic work) ----
  hipMemsetAsync(cursor, 0, (size_t)NNODES*4, stream);
  k_hist<<<(NEDGES+255)/256, 256, 0, stream>>>(dstI, cursor);
  int nb = (NNODES+255)/256;
  k_scan1<<<nb, 256, 0, stream>>>(cursor, rowptr, bsum);
  k_scan2<<<1, 512, 0, stream>>>(bsum, boff, nb);
  k_scan3<<<(NNODES+255)/256, 256, 0, stream>>>(rowptr, boff);
  k_curcopy<<<(NNODES+255)/256, 256, 0, stream>>>(rowptr, cursor);
  k_fill<<<(NEDGES+255)/256, 256, 0, stream>>>(srcI, dstI, ea, cursor, perm, srcp, eaperm);
  k_selfe<<<NLAYER, EMBD, 0, stream>>>(eb1, ew2, eb2, selfe);

  const int gx = (NNODES + 63)/64;

  // ---- input MLP: h = leaky(x@iw1+ib1)@iw2+ib2 ----
  k_gemm<float,1,false,false,false><<<dim3(gx,1), 256, 0, stream>>>(
      x, NNODES, XDIM, iw1, EMBD, ib1, nullptr, S1, nullptr, EMBD, nullptr);
  k_gemm<float,0,false,false,false><<<dim3(gx,1), 256, 0, stream>>>(
      S1, NNODES, EMBD, iw2, EMBD, ib2, nullptr, hbuf, nullptr, EMBD, nullptr);

  for (int l=0; l<NLAYER; ++l){
    hipMemsetAsync(stats, 0, 2*EMBD*4, stream);
    // S1 = segment_sum(leaky(ea@ew1+eb1)); base = segment_sum(h[src]) + h + self_e + deg*eb2
    k_edge<<<NNODES/4, 256, 0, stream>>>(
        hbuf, rowptr, perm, srcp, ea, eaperm,
        ew1 + (size_t)l*EDIM*EMBD, eb1 + l*EMBD, eb2 + l*EMBD, selfe + l*EMBD,
        S1, base);
    // aggr (into base) = S1 @ ew2 + base
    k_gemm<float,0,true,false,false><<<dim3(gx,1), 256, 0, stream>>>(
        S1, NNODES, EMBD, ew2 + (size_t)l*EMBD*EMBD, EMBD, nullptr, base, base, nullptr, EMBD, nullptr);
    // t = relu(aggr @ mw1 + mb1)  (bf16, [N,256])
    k_gemm<float,2,false,false,true><<<dim3(gx,2), 256, 0, stream>>>(
        base, NNODES, EMBD, mw1 + (size_t)l*EMBD*2*EMBD, 2*EMBD, mb1 + l*2*EMBD,
        nullptr, nullptr, tbuf, 2*EMBD, nullptr);
    // hh (into S1) = t @ mw2 + mb2, with BN partial sums
    k_gemm<__hip_bfloat16,0,false,true,false><<<dim3(gx,1), 256, 0, stream>>>(
        tbuf, NNODES, 2*EMBD, mw2 + (size_t)l*2*EMBD*EMBD, EMBD, mb2 + l*EMBD,
        nullptr, S1, nullptr, EMBD, stats);
    // BN normalize (+relu except last); last layer writes d_out
    float* outp = (l == NLAYER-1) ? (float*)d_out : hbuf;
    k_bn<<<(NNODES*(EMBD/4)+255)/256, 256, 0, stream>>>(
        S1, stats, gamma + l*EMBD, beta + l*EMBD, outp, (l < NLAYER-1) ? 1 : 0);
  }
}

// Round 2
// 2467.131 us; speedup vs baseline: 1.9412x; 1.9412x over previous
//
#include <hip/hip_runtime.h>
#include <hip/hip_bf16.h>
#include <cstdint>
#include <cstddef>

#define NNODES 100000
#define NEDGES 1600000
#define EMBD 128
#define NLAYER 5
#define XDIM 178
#define EDIM 18
#define BNEPS 1e-5f

typedef __attribute__((ext_vector_type(8))) short short8;
typedef __attribute__((ext_vector_type(8))) unsigned short ushort8;
typedef __attribute__((ext_vector_type(4))) float f32x4;

static __device__ __forceinline__ float leakyf(float v){ return v > 0.f ? v : 0.1f*v; }
static __device__ __forceinline__ unsigned short f2b(float v){
  __hip_bfloat16 b = __float2bfloat16(v);
  return *reinterpret_cast<unsigned short*>(&b);
}
static __device__ __forceinline__ float b2f(unsigned short u){
  __hip_bfloat16 b = *reinterpret_cast<__hip_bfloat16*>(&u);
  return __bfloat162float(b);
}

// ---------------- CSR build ----------------
__global__ __launch_bounds__(256) void k_hist(const int* __restrict__ dst, int* __restrict__ cnt){
  int e = blockIdx.x*256 + threadIdx.x;
  if (e < NEDGES) atomicAdd(&cnt[dst[e]], 1);
}

__global__ __launch_bounds__(256) void k_scan1(const int* __restrict__ cnt, int* __restrict__ rowptr,
                                               int* __restrict__ bsum){
  __shared__ int s[256];
  int t = threadIdx.x, i = blockIdx.x*256 + t;
  int v = (i < NNODES) ? cnt[i] : 0;
  s[t] = v; __syncthreads();
  for (int off=1; off<256; off<<=1){
    int x = (t>=off) ? s[t-off] : 0; __syncthreads();
    s[t] += x; __syncthreads();
  }
  if (i < NNODES) rowptr[i+1] = s[t];
  if (t == 255) bsum[blockIdx.x] = s[t];
}

__global__ __launch_bounds__(512) void k_scan2(const int* __restrict__ bsum, int* __restrict__ boff, int nb){
  __shared__ int s[512];
  int t = threadIdx.x;
  int v = (t < nb) ? bsum[t] : 0;
  s[t] = v; __syncthreads();
  for (int off=1; off<512; off<<=1){
    int x = (t>=off) ? s[t-off] : 0; __syncthreads();
    s[t] += x; __syncthreads();
  }
  if (t < nb) boff[t] = s[t] - v;
}

__global__ __launch_bounds__(256) void k_scan3(int* __restrict__ rowptr, const int* __restrict__ boff){
  int i = blockIdx.x*256 + threadIdx.x;
  if (i < NNODES) rowptr[i+1] += boff[i>>8];
  if (i == 0) rowptr[0] = 0;
}

__global__ __launch_bounds__(256) void k_curcopy(const int* __restrict__ rowptr, int* __restrict__ cursor){
  int i = blockIdx.x*256 + threadIdx.x;
  if (i < NNODES) cursor[i] = rowptr[i];
}

__global__ __launch_bounds__(256) void k_fill(const int* __restrict__ src, const int* __restrict__ dst,
                                              const float* __restrict__ ea, int* __restrict__ cursor,
                                              int* __restrict__ perm, int* __restrict__ srcp,
                                              float* __restrict__ eap){
  int e = blockIdx.x*256 + threadIdx.x;
  if (e >= NEDGES) return;
  int pos = atomicAdd(&cursor[dst[e]], 1);
  perm[pos] = e;
  srcp[pos] = src[e];
  if (eap){
    const float* a = ea + (size_t)e*EDIM;
    float* o = eap + (size_t)pos*EDIM;
    #pragma unroll
    for (int k=0;k<EDIM;++k) o[k] = a[k];
  }
}

// self_e[l] = leaky(eb1[l]) @ ew2[l] + eb2[l]
__global__ __launch_bounds__(128) void k_selfe(const float* __restrict__ eb1, const float* __restrict__ ew2,
                                               const float* __restrict__ eb2, float* __restrict__ selfe){
  int l = blockIdx.x, c = threadIdx.x;
  const float* b1 = eb1 + l*EMBD;
  const float* w2 = ew2 + (size_t)l*EMBD*EMBD;
  float acc = eb2[l*EMBD + c];
  for (int j=0;j<EMBD;++j) acc += leakyf(b1[j]) * w2[j*EMBD + c];
  selfe[l*EMBD + c] = acc;
}

// Wc[l] = ew2[l] @ mw1[l]  ([128][256] fp32)
__global__ __launch_bounds__(256) void k_wc(const float* __restrict__ ew2, const float* __restrict__ mw1,
                                            float* __restrict__ wc){
  int idx = blockIdx.x*256 + threadIdx.x;       // 5*128*256
  int l = idx >> 15, rem = idx & 32767;
  int i = rem >> 8, n = rem & 255;
  const float* e = ew2 + (size_t)l*EMBD*EMBD + i*EMBD;
  const float* m = mw1 + (size_t)l*EMBD*2*EMBD + n;
  float acc = 0.f;
  #pragma unroll 4
  for (int j=0;j<EMBD;++j) acc += e[j]*m[(size_t)j*2*EMBD];
  wc[idx] = acc;
}

// pack B [Kpad x N] (rows: s1[0:rows1], s2[rows1:Kreal], zero beyond) into
// hi/lo bf16 planes laid out [ks][n][kk] (kk = k&31), lo plane at +Kpad*N.
__global__ __launch_bounds__(256) void k_pack(const float* __restrict__ s1, int rows1,
                                              const float* __restrict__ s2, int Kreal,
                                              int Kpad, int N, __hip_bfloat16* __restrict__ out){
  int idx = blockIdx.x*256 + threadIdx.x;
  if (idx >= Kpad*N) return;
  int k = idx / N, n = idx - k*N;
  float v = 0.f;
  if (k < rows1) v = s1[(size_t)k*N + n];
  else if (k < Kreal) v = s2[(size_t)(k-rows1)*N + n];
  unsigned short hi = f2b(v);
  unsigned short lo = f2b(v - b2f(hi));
  size_t o = (size_t)(k>>5)*N*32 + (size_t)n*32 + (k&31);
  unsigned short* po = (unsigned short*)out;
  po[o] = hi;
  po[(size_t)Kpad*N + o] = lo;
}

// ------------- per-layer edge + aggregate (one wave per dst node) -------------
__global__ __launch_bounds__(256) void k_edge(
    const float* __restrict__ h, const int* __restrict__ rowptr,
    const int* __restrict__ perm, const int* __restrict__ srcp,
    const float* __restrict__ edge_attr, const float* __restrict__ eaperm,
    const float* __restrict__ ew1l, const float* __restrict__ eb1l,
    const float* __restrict__ eb2l, const float* __restrict__ selfel,
    float* __restrict__ S1, float* __restrict__ base)
{
  __shared__ float w1s[EDIM*EMBD];
  __shared__ float b1s[EMBD];
  int tid = threadIdx.x;
  for (int i = tid; i < EDIM*EMBD; i += 256) w1s[i] = ew1l[i];
  if (tid < EMBD) b1s[tid] = eb1l[tid];
  __syncthreads();
  int lane = tid & 63;
  int node = blockIdx.x*4 + (tid >> 6);
  if (node >= NNODES) return;
  int rs = rowptr[node], re = rowptr[node+1];
  int c0 = lane*2;
  float s1x=0.f, s1y=0.f, bx=0.f, by=0.f;
  for (int i = rs; i < re; ++i){
    int s = __builtin_amdgcn_readfirstlane(srcp[i]);
    const float* ea;
    if (eaperm){
      ea = eaperm + (size_t)__builtin_amdgcn_readfirstlane(i)*EDIM;
    } else {
      ea = edge_attr + (size_t)__builtin_amdgcn_readfirstlane(perm[i])*EDIM;
    }
    float2 hs = *(const float2*)(h + (size_t)s*EMBD + c0);
    bx += hs.x; by += hs.y;
    float d0 = b1s[c0], d1 = b1s[c0+1];
    #pragma unroll
    for (int k=0;k<EDIM;++k){
      float av = ea[k];
      d0 += av * w1s[k*EMBD + c0];
      d1 += av * w1s[k*EMBD + c0 + 1];
    }
    s1x += leakyf(d0); s1y += leakyf(d1);
  }
  float deg = (float)(re - rs);
  float2 hv = *(const float2*)(h + (size_t)node*EMBD + c0);
  *(float2*)(S1 + (size_t)node*EMBD + c0) = make_float2(s1x, s1y);
  float bvx = bx + hv.x + selfel[c0]   + deg*eb2l[c0];
  float bvy = by + hv.y + selfel[c0+1] + deg*eb2l[c0+1];
  *(float2*)(base + (size_t)node*EMBD + c0) = make_float2(bvx, bvy);
}

// ------------- MFMA GEMM: C = act(A[M,K] @ B + bias), split-bf16 precision -------------
// BM=128 tile, 512 threads = 8 waves (WGM x WGN), per-wave MFxNF 16x16 frags.
// A: fp32 (split hi/lo) or bf16 (hi only). B: pre-packed split-bf16 planes.
// ACT: 0 none, 1 leaky, 2 relu.
template<int BN, int WGM, int WGN, bool ALO, int ACT, bool STATS, bool OBF16, bool CONCAT, bool KCHK, bool ABF16>
__global__ __launch_bounds__(512) void k_mgemm(
    const float* __restrict__ Af, const float* __restrict__ A1,
    const __hip_bfloat16* __restrict__ Ab,
    int M, int Kreal, int Kpad, int lda,
    const __hip_bfloat16* __restrict__ Bp,
    const float* __restrict__ bias,
    float* __restrict__ Cf, __hip_bfloat16* __restrict__ Cb, int ldc,
    float* __restrict__ stats)
{
  static_assert(WGM*WGN == 8, "8 waves");
  constexpr int BM = 128;
  constexpr int MF = BM/(16*WGM);
  constexpr int NF = BN/(16*WGN);
  constexpr int LDS_ROW = 40;  // padded ushorts per 32-elem row
  __shared__ __align__(16) unsigned short Ah[BM*LDS_ROW];
  __shared__ __align__(16) unsigned short Al[ALO ? BM*LDS_ROW : 8];
  __shared__ float ssum[STATS ? BN : 4];
  __shared__ float ssq [STATS ? BN : 4];

  int tid = threadIdx.x;
  int row0 = blockIdx.x*BM;
  int w = tid >> 6, lane = tid & 63;
  int wm = w / WGN, wn = w % WGN;
  int lr = lane & 15, kb = lane >> 4;
  int wrow = wm*MF*16, wcol = wn*NF*16;

  if (STATS && tid < BN){ ssum[tid] = 0.f; ssq[tid] = 0.f; }

  f32x4 acc[MF][NF];
  #pragma unroll
  for (int a=0;a<MF;++a)
    #pragma unroll
    for (int b=0;b<NF;++b) acc[a][b] = (f32x4)0.f;

  const size_t planeSz = (size_t)Kpad*BN;
  int sr = tid >> 2;            // 0..127 staging row
  int skq = (tid & 3)*8;        // 0,8,16,24
  int grow = row0 + sr;
  const int KS = Kpad >> 5;

  for (int ks = 0; ks < KS; ++ks){
    int k0 = ks << 5;
    int kg = k0 + skq;
    ushort8 hv, lv;
    if (ABF16){
      short8 raw = (short8)0;
      if (grow < M) raw = *reinterpret_cast<const short8*>((const unsigned short*)Ab + (size_t)grow*lda + kg);
      hv = *reinterpret_cast<ushort8*>(&raw);
    } else {
      float v[8];
      if (KCHK){
        #pragma unroll
        for (int i=0;i<8;++i)
          v[i] = (grow < M && kg+i < Kreal) ? Af[(size_t)grow*lda + kg + i] : 0.f;
      } else {
        const float* s;
        if (CONCAT) s = (kg < EMBD) ? (Af + (size_t)grow*lda + kg) : (A1 + (size_t)grow*lda + (kg - EMBD));
        else        s = Af + (size_t)grow*lda + kg;
        float4 p0 = make_float4(0,0,0,0), p1 = make_float4(0,0,0,0);
        if (grow < M){ p0 = *(const float4*)s; p1 = *(const float4*)(s+4); }
        v[0]=p0.x; v[1]=p0.y; v[2]=p0.z; v[3]=p0.w;
        v[4]=p1.x; v[5]=p1.y; v[6]=p1.z; v[7]=p1.w;
      }
      #pragma unroll
      for (int i=0;i<8;++i){
        unsigned short h16 = f2b(v[i]);
        hv[i] = h16;
        if (ALO) lv[i] = f2b(v[i] - b2f(h16));
      }
    }
    __syncthreads();
    *reinterpret_cast<ushort8*>(&Ah[sr*LDS_ROW + skq]) = hv;
    if (ALO && !ABF16) *reinterpret_cast<ushort8*>(&Al[sr*LDS_ROW + skq]) = lv;
    __syncthreads();

    short8 ah[MF], al[MF];
    #pragma unroll
    for (int mf=0; mf<MF; ++mf){
      int r = (wrow + mf*16 + lr)*LDS_ROW + kb*8;
      ah[mf] = *reinterpret_cast<const short8*>(&Ah[r]);
      if (ALO) al[mf] = *reinterpret_cast<const short8*>(&Al[r]);
    }
    const unsigned short* bb = (const unsigned short*)Bp + (size_t)ks*BN*32;
    short8 bh[NF], bl[NF];
    #pragma unroll
    for (int nf=0; nf<NF; ++nf){
      size_t off = (size_t)(wcol + nf*16 + lr)*32 + kb*8;
      bh[nf] = *reinterpret_cast<const short8*>(bb + off);
      bl[nf] = *reinterpret_cast<const short8*>(bb + planeSz + off);
    }
    #pragma unroll
    for (int mf=0; mf<MF; ++mf){
      #pragma unroll
      for (int nf=0; nf<NF; ++nf){
        acc[mf][nf] = __builtin_amdgcn_mfma_f32_16x16x32_bf16(ah[mf], bh[nf], acc[mf][nf], 0, 0, 0);
        acc[mf][nf] = __builtin_amdgcn_mfma_f32_16x16x32_bf16(ah[mf], bl[nf], acc[mf][nf], 0, 0, 0);
        if (ALO)
          acc[mf][nf] = __builtin_amdgcn_mfma_f32_16x16x32_bf16(al[mf], bh[nf], acc[mf][nf], 0, 0, 0);
      }
    }
  }

  // epilogue
  float bcol[NF];
  #pragma unroll
  for (int nf=0; nf<NF; ++nf) bcol[nf] = bias ? bias[wcol + nf*16 + lr] : 0.f;
  float s[NF], sq[NF];
  #pragma unroll
  for (int nf=0; nf<NF; ++nf){ s[nf]=0.f; sq[nf]=0.f; }

  #pragma unroll
  for (int mf=0; mf<MF; ++mf){
    #pragma unroll
    for (int j=0; j<4; ++j){
      int r = row0 + wrow + mf*16 + kb*4 + j;
      if (r < M){
        #pragma unroll
        for (int nf=0; nf<NF; ++nf){
          int c = wcol + nf*16 + lr;
          float v = acc[mf][nf][j] + bcol[nf];
          if (ACT == 1) v = leakyf(v);
          if (ACT == 2) v = fmaxf(v, 0.f);
          if (OBF16) Cb[(size_t)r*ldc + c] = __float2bfloat16(v);
          else       Cf[(size_t)r*ldc + c] = v;
          if (STATS){ s[nf] += v; sq[nf] += v*v; }
        }
      }
    }
  }
  if (STATS){
    #pragma unroll
    for (int nf=0; nf<NF; ++nf){
      atomicAdd(&ssum[wcol + nf*16 + lr], s[nf]);
      atomicAdd(&ssq [wcol + nf*16 + lr], sq[nf]);
    }
    __syncthreads();
    if (tid < BN){
      atomicAdd(&stats[tid], ssum[tid]);
      atomicAdd(&stats[BN + tid], ssq[tid]);
    }
  }
}

// ------------- BatchNorm normalize (+optional relu) -------------
__global__ __launch_bounds__(256) void k_bn(const float* __restrict__ hh, const float* __restrict__ stats,
                                            const float* __restrict__ gamma, const float* __restrict__ beta,
                                            float* __restrict__ out, int dorelu){
  int idx = blockIdx.x*256 + threadIdx.x;
  if (idx >= NNODES*(EMBD/4)) return;
  int c0 = (idx & (EMBD/4 - 1)) * 4;
  float4 v = *(const float4*)(hh + (size_t)idx*4);
  float o[4] = {v.x, v.y, v.z, v.w};
  const float invN = 1.f / (float)NNODES;
  #pragma unroll
  for (int i=0;i<4;++i){
    int c = c0 + i;
    float mean = stats[c] * invN;
    float var  = stats[EMBD + c] * invN - mean*mean;
    float inv  = rsqrtf(fmaxf(var, 0.f) + BNEPS);
    float y = (o[i] - mean) * inv * gamma[c] + beta[c];
    if (dorelu) y = fmaxf(y, 0.f);
    o[i] = y;
  }
  *(float4*)(out + (size_t)idx*4) = make_float4(o[0],o[1],o[2],o[3]);
}

// ---------------- launcher ----------------
extern "C" void kernel_launch(void* const* d_in, const int* in_sizes, int n_in,
                              void* d_out, int out_size, void* d_ws, size_t ws_size,
                              hipStream_t stream)
{
  const float* x   = (const float*)d_in[0];
  const float* ea  = (const float*)d_in[1];
  const float* iw1 = (const float*)d_in[2];
  const float* ib1 = (const float*)d_in[3];
  const float* iw2 = (const float*)d_in[4];
  const float* ib2 = (const float*)d_in[5];
  const float* ew1 = (const float*)d_in[6];
  const float* eb1 = (const float*)d_in[7];
  const float* ew2 = (const float*)d_in[8];
  const float* eb2 = (const float*)d_in[9];
  const float* mw1 = (const float*)d_in[10];
  const float* mb1 = (const float*)d_in[11];
  const float* mw2 = (const float*)d_in[12];
  const float* mb2 = (const float*)d_in[13];
  const float* gamma = (const float*)d_in[14];
  const float* beta  = (const float*)d_in[15];
  const int* eidx = (const int*)d_in[16];
  const int* srcI = eidx;
  const int* dstI = eidx + NEDGES;

  char* p = (char*)d_ws;
  auto alloc = [&](size_t bytes)->char*{
    char* r = p; p += (bytes + 255) & ~(size_t)255; return r;
  };
  float* hbuf  = (float*)alloc((size_t)NNODES*EMBD*4);
  float* S1    = (float*)alloc((size_t)NNODES*EMBD*4);
  float* base  = (float*)alloc((size_t)NNODES*EMBD*4);
  __hip_bfloat16* tbuf = (__hip_bfloat16*)alloc((size_t)NNODES*2*EMBD*2);
  int* perm   = (int*)alloc((size_t)NEDGES*4);
  int* srcp   = (int*)alloc((size_t)NEDGES*4);
  int* rowptr = (int*)alloc((size_t)(NNODES+1)*4);
  int* cursor = (int*)alloc((size_t)NNODES*4);
  int* bsum   = (int*)alloc(4096);
  int* boff   = (int*)alloc(4096);
  float* selfe = (float*)alloc(NLAYER*EMBD*4);
  float* stats = (float*)alloc(2*EMBD*4);
  float* wc    = (float*)alloc((size_t)NLAYER*EMBD*2*EMBD*4);            // 5 x 128 x 256 fp32
  __hip_bfloat16* Bi1 = (__hip_bfloat16*)alloc((size_t)192*EMBD*2*2);    // hi+lo
  __hip_bfloat16* Bi2 = (__hip_bfloat16*)alloc((size_t)EMBD*EMBD*2*2);
  __hip_bfloat16* B1  = (__hip_bfloat16*)alloc((size_t)NLAYER*256*256*2*2);
  __hip_bfloat16* B2  = (__hip_bfloat16*)alloc((size_t)NLAYER*256*EMBD*2*2);
  size_t used = (size_t)(p - (char*)d_ws);
  float* eaperm = nullptr;
  if (ws_size >= used + (size_t)NEDGES*EDIM*4 + 256)
    eaperm = (float*)alloc((size_t)NEDGES*EDIM*4);

  // ---- CSR build ----
  hipMemsetAsync(cursor, 0, (size_t)NNODES*4, stream);
  k_hist<<<(NEDGES+255)/256, 256, 0, stream>>>(dstI, cursor);
  int nb = (NNODES+255)/256;
  k_scan1<<<nb, 256, 0, stream>>>(cursor, rowptr, bsum);
  k_scan2<<<1, 512, 0, stream>>>(bsum, boff, nb);
  k_scan3<<<(NNODES+255)/256, 256, 0, stream>>>(rowptr, boff);
  k_curcopy<<<(NNODES+255)/256, 256, 0, stream>>>(rowptr, cursor);
  k_fill<<<(NEDGES+255)/256, 256, 0, stream>>>(srcI, dstI, ea, cursor, perm, srcp, eaperm);
  k_selfe<<<NLAYER, EMBD, 0, stream>>>(eb1, ew2, eb2, selfe);

  // ---- weight prep: Wc = ew2@mw1, pack all B matrices to split-bf16 ----
  k_wc<<<(NLAYER*EMBD*2*EMBD)/256, 256, 0, stream>>>(ew2, mw1, wc);
  k_pack<<<(192*EMBD+255)/256, 256, 0, stream>>>(iw1, XDIM, iw1, XDIM, 192, EMBD, Bi1);
  k_pack<<<(EMBD*EMBD+255)/256, 256, 0, stream>>>(iw2, EMBD, iw2, EMBD, EMBD, EMBD, Bi2);
  for (int l=0; l<NLAYER; ++l){
    k_pack<<<(256*256+255)/256, 256, 0, stream>>>(
        wc + (size_t)l*EMBD*2*EMBD, EMBD, mw1 + (size_t)l*EMBD*2*EMBD, 256, 256, 256,
        B1 + (size_t)l*256*256*2);
    k_pack<<<(256*EMBD+255)/256, 256, 0, stream>>>(
        mw2 + (size_t)l*2*EMBD*EMBD, 256, mw2, 256, 256, EMBD,
        B2 + (size_t)l*256*EMBD*2);
  }

  const int gx = (NNODES + 127)/128;

  // ---- input MLP ----
  // S1 = leaky(x@iw1 + ib1)   [K=178 pad 192]
  k_mgemm<128,4,2, true,1,false,false,false,true ,false><<<gx, 512, 0, stream>>>(
      x, nullptr, nullptr, NNODES, XDIM, 192, XDIM, Bi1, ib1, S1, nullptr, EMBD, nullptr);
  // h = S1@iw2 + ib2
  k_mgemm<128,4,2, true,0,false,false,false,false,false><<<gx, 512, 0, stream>>>(
      S1, nullptr, nullptr, NNODES, EMBD, EMBD, EMBD, Bi2, ib2, hbuf, nullptr, EMBD, nullptr);

  for (int l=0; l<NLAYER; ++l){
    hipMemsetAsync(stats, 0, 2*EMBD*4, stream);
    // S1 = segsum(leaky(ea@ew1+eb1)); base = segsum(h[src]) + h + self_e + deg*eb2
    k_edge<<<NNODES/4, 256, 0, stream>>>(
        hbuf, rowptr, perm, srcp, ea, eaperm,
        ew1 + (size_t)l*EDIM*EMBD, eb1 + l*EMBD, eb2 + l*EMBD, selfe + l*EMBD,
        S1, base);
    // t = relu([S1|base] @ [Wc;mw1] + mb1)  -> bf16 [N,256]
    k_mgemm<256,2,4, true,2,false,true ,true ,false,false><<<gx, 512, 0, stream>>>(
        S1, base, nullptr, NNODES, 256, 256, EMBD, B1 + (size_t)l*256*256*2,
        mb1 + l*2*EMBD, nullptr, tbuf, 2*EMBD, nullptr);
    // hh (into S1) = t @ mw2 + mb2, fused BN stats
    k_mgemm<128,4,2, false,0,true ,false,false,false,true ><<<gx, 512, 0, stream>>>(
        nullptr, nullptr, tbuf, NNODES, 256, 256, 2*EMBD, B2 + (size_t)l*256*EMBD*2,
        mb2 + l*EMBD, S1, nullptr, EMBD, stats);
    // BN normalize (+relu except last)
    float* outp = (l == NLAYER-1) ? (float*)d_out : hbuf;
    k_bn<<<(NNODES*(EMBD/4)+255)/256, 256, 0, stream>>>(
        S1, stats, gamma + l*EMBD, beta + l*EMBD, outp, (l < NLAYER-1) ? 1 : 0);
  }
}

// Round 3
// 2098.975 us; speedup vs baseline: 2.2817x; 1.1754x over previous
//
#include <hip/hip_runtime.h>
#include <hip/hip_bf16.h>
#include <cstdint>
#include <cstddef>

#define NNODES 100000
#define NEDGES 1600000
#define EMBD 128
#define NLAYER 5
#define XDIM 178
#define EDIM 18
#define BNEPS 1e-5f

typedef __attribute__((ext_vector_type(8))) short short8;
typedef __attribute__((ext_vector_type(8))) unsigned short ushort8;
typedef __attribute__((ext_vector_type(4))) float f32x4;

static __device__ __forceinline__ float leakyf(float v){ return v > 0.f ? v : 0.1f*v; }
static __device__ __forceinline__ unsigned short f2b(float v){
  __hip_bfloat16 b = __float2bfloat16(v);
  return *reinterpret_cast<unsigned short*>(&b);
}
static __device__ __forceinline__ float b2f(unsigned short u){
  __hip_bfloat16 b = *reinterpret_cast<__hip_bfloat16*>(&u);
  return __bfloat162float(b);
}

// ---------------- CSR build ----------------
__global__ __launch_bounds__(256) void k_hist(const int* __restrict__ dst, int* __restrict__ cnt){
  int e = blockIdx.x*256 + threadIdx.x;
  if (e < NEDGES) atomicAdd(&cnt[dst[e]], 1);
}

__global__ __launch_bounds__(256) void k_scan1(const int* __restrict__ cnt, int* __restrict__ rowptr,
                                               int* __restrict__ bsum){
  __shared__ int s[256];
  int t = threadIdx.x, i = blockIdx.x*256 + t;
  int v = (i < NNODES) ? cnt[i] : 0;
  s[t] = v; __syncthreads();
  for (int off=1; off<256; off<<=1){
    int x = (t>=off) ? s[t-off] : 0; __syncthreads();
    s[t] += x; __syncthreads();
  }
  if (i < NNODES) rowptr[i+1] = s[t];
  if (t == 255) bsum[blockIdx.x] = s[t];
}

__global__ __launch_bounds__(512) void k_scan2(const int* __restrict__ bsum, int* __restrict__ boff, int nb){
  __shared__ int s[512];
  int t = threadIdx.x;
  int v = (t < nb) ? bsum[t] : 0;
  s[t] = v; __syncthreads();
  for (int off=1; off<512; off<<=1){
    int x = (t>=off) ? s[t-off] : 0; __syncthreads();
    s[t] += x; __syncthreads();
  }
  if (t < nb) boff[t] = s[t] - v;
}

__global__ __launch_bounds__(256) void k_scan3(int* __restrict__ rowptr, const int* __restrict__ boff){
  int i = blockIdx.x*256 + threadIdx.x;
  if (i < NNODES) rowptr[i+1] += boff[i>>8];
  if (i == 0) rowptr[0] = 0;
}

__global__ __launch_bounds__(256) void k_curcopy(const int* __restrict__ rowptr, int* __restrict__ cursor){
  int i = blockIdx.x*256 + threadIdx.x;
  if (i < NNODES) cursor[i] = rowptr[i];
}

// new-path fill: srcp + bf16-packed ea rows (24 shorts: 18 attrs, slot18=1.0, rest 0)
__global__ __launch_bounds__(256) void k_fill_new(const int* __restrict__ src, const int* __restrict__ dst,
                                                  const float* __restrict__ ea, int* __restrict__ cursor,
                                                  int* __restrict__ srcp, unsigned short* __restrict__ eap24){
  int e = blockIdx.x*256 + threadIdx.x;
  if (e >= NEDGES) return;
  int pos = atomicAdd(&cursor[dst[e]], 1);
  srcp[pos] = src[e];
  const float* a = ea + (size_t)e*EDIM;
  ushort8 r0, r1, r2;
  #pragma unroll
  for (int k=0;k<8;++k)  r0[k] = f2b(a[k]);
  #pragma unroll
  for (int k=0;k<8;++k)  r1[k] = f2b(a[8+k]);
  #pragma unroll
  for (int k=0;k<8;++k)  r2[k] = 0;
  r2[0] = f2b(a[16]); r2[1] = f2b(a[17]);
  r2[2] = 0x3F80;   // bf16 1.0 at k=18 -> bias slot
  unsigned short* o = eap24 + (size_t)pos*24;
  *reinterpret_cast<ushort8*>(o)      = r0;
  *reinterpret_cast<ushort8*>(o + 8)  = r1;
  *reinterpret_cast<ushort8*>(o + 16) = r2;
}

// old-path fill (fallback)
__global__ __launch_bounds__(256) void k_fill(const int* __restrict__ src, const int* __restrict__ dst,
                                              const float* __restrict__ ea, int* __restrict__ cursor,
                                              int* __restrict__ perm, int* __restrict__ srcp,
                                              float* __restrict__ eap){
  int e = blockIdx.x*256 + threadIdx.x;
  if (e >= NEDGES) return;
  int pos = atomicAdd(&cursor[dst[e]], 1);
  perm[pos] = e;
  srcp[pos] = src[e];
  if (eap){
    const float* a = ea + (size_t)e*EDIM;
    float* o = eap + (size_t)pos*EDIM;
    #pragma unroll
    for (int k=0;k<EDIM;++k) o[k] = a[k];
  }
}

// self_e[l] = leaky(eb1[l]) @ ew2[l] + eb2[l]
__global__ __launch_bounds__(128) void k_selfe(const float* __restrict__ eb1, const float* __restrict__ ew2,
                                               const float* __restrict__ eb2, float* __restrict__ selfe){
  int l = blockIdx.x, c = threadIdx.x;
  const float* b1 = eb1 + l*EMBD;
  const float* w2 = ew2 + (size_t)l*EMBD*EMBD;
  float acc = eb2[l*EMBD + c];
  for (int j=0;j<EMBD;++j) acc += leakyf(b1[j]) * w2[j*EMBD + c];
  selfe[l*EMBD + c] = acc;
}

// Wc[l] = ew2[l] @ mw1[l]  ([128][256] fp32)
__global__ __launch_bounds__(256) void k_wc(const float* __restrict__ ew2, const float* __restrict__ mw1,
                                            float* __restrict__ wc){
  int idx = blockIdx.x*256 + threadIdx.x;       // 5*128*256
  int l = idx >> 15, rem = idx & 32767;
  int i = rem >> 8, n = rem & 255;
  const float* e = ew2 + (size_t)l*EMBD*EMBD + i*EMBD;
  const float* m = mw1 + (size_t)l*EMBD*2*EMBD + n;
  float acc = 0.f;
  #pragma unroll 4
  for (int j=0;j<EMBD;++j) acc += e[j]*m[(size_t)j*2*EMBD];
  wc[idx] = acc;
}

// pack B [Kpad x N] into hi/lo bf16 planes laid out [ks][n][kk]
__global__ __launch_bounds__(256) void k_pack(const float* __restrict__ s1, int rows1,
                                              const float* __restrict__ s2, int Kreal,
                                              int Kpad, int N, __hip_bfloat16* __restrict__ out){
  int idx = blockIdx.x*256 + threadIdx.x;
  if (idx >= Kpad*N) return;
  int k = idx / N, n = idx - k*N;
  float v = 0.f;
  if (k < rows1) v = s1[(size_t)k*N + n];
  else if (k < Kreal) v = s2[(size_t)(k-rows1)*N + n];
  unsigned short hi = f2b(v);
  unsigned short lo = f2b(v - b2f(hi));
  size_t o = (size_t)(k>>5)*N*32 + (size_t)n*32 + (k&31);
  unsigned short* po = (unsigned short*)out;
  po[o] = hi;
  po[(size_t)Kpad*N + o] = lo;
}

// ------------- NEW edge kernel: MFMA edge-MLP + deep-MLP h gather -------------
// One wave per node (persistent, grid-stride). Batch 16 edges per MFMA chunk.
// A[16 x 32]: rows=edges, k=0..17 ea(bf16), k=18 const 1.0 (bias), rest 0.
// B[32 x 128]: ew1 (+eb1 at k=18), split hi/lo bf16 held in registers.
__global__ __launch_bounds__(256) void k_edge_mfma(
    const float* __restrict__ h, const int* __restrict__ rowptr,
    const int* __restrict__ srcp, const unsigned short* __restrict__ eap24,
    const float* __restrict__ ew1l, const float* __restrict__ eb1l,
    const float* __restrict__ eb2l, const float* __restrict__ selfel,
    float* __restrict__ S1, float* __restrict__ base)
{
  int tid = threadIdx.x;
  int lane = tid & 63;
  int lr = lane & 15, kb = lane >> 4;
  int c2 = lane*2;

  // Build B fragments once per wave: col = nf*16+lr, k = kb*8+j
  short8 bh[8], bl[8];
  #pragma unroll
  for (int nf=0; nf<8; ++nf){
    int col = nf*16 + lr;
    ushort8 hh8, ll8;
    #pragma unroll
    for (int j=0;j<8;++j){
      int k = kb*8 + j;
      float v = 0.f;
      if (k < EDIM) v = ew1l[k*EMBD + col];
      else if (k == EDIM) v = eb1l[col];
      unsigned short hi = f2b(v);
      hh8[j] = hi;
      ll8[j] = f2b(v - b2f(hi));
    }
    bh[nf] = *reinterpret_cast<short8*>(&hh8);
    bl[nf] = *reinterpret_cast<short8*>(&ll8);
  }
  float eb2x = eb2l[c2], eb2y = eb2l[c2+1];
  float sfx = selfel[c2], sfy = selfel[c2+1];

  int wid = __builtin_amdgcn_readfirstlane(blockIdx.x*4 + (tid>>6));
  const int NW = gridDim.x*4;
  for (int node = wid; node < NNODES; node += NW){
    int rs = rowptr[node], re = rowptr[node+1];
    float s1p[8];
    #pragma unroll
    for (int nf=0;nf<8;++nf) s1p[nf]=0.f;
    float bx=0.f, by=0.f;

    for (int c0 = rs; c0 < re; c0 += 16){
      int cnt = re - c0;                      // wave-uniform
      int idx = c0 + lr; if (idx > re-1) idx = re-1;
      int srcv = srcp[idx];
      // A fragment (16B per lane), kb==3 -> zeros, invalid rows -> zeros
      short8 af = (short8)0;
      if (kb < 3){
        ushort8 t = *reinterpret_cast<const ushort8*>(eap24 + (size_t)idx*24 + kb*8);
        af = *reinterpret_cast<short8*>(&t);
      }
      if (lr >= cnt) af = (short8)0;

      // edge MLP hidden: d = A @ [ew1;eb1] (hi+lo), leaky-accumulate
      #pragma unroll
      for (int nf=0;nf<8;++nf){
        f32x4 acc = (f32x4)0.f;
        acc = __builtin_amdgcn_mfma_f32_16x16x32_bf16(af, bl[nf], acc, 0,0,0);
        acc = __builtin_amdgcn_mfma_f32_16x16x32_bf16(af, bh[nf], acc, 0,0,0);
        #pragma unroll
        for (int j=0;j<4;++j){
          float v = acc[j];                   // leaky(v) = 0.55v + 0.45|v|
          s1p[nf] = fmaf(0.55f, v, s1p[nf]);
          s1p[nf] = fmaf(0.45f, fabsf(v), s1p[nf]);
        }
      }

      // h gather: quad-granular (uniform branches), per-e mask
      #pragma unroll
      for (int q=0;q<4;++q){
        if (q*4 < cnt){
          int s0 = __builtin_amdgcn_readlane(srcv, q*4+0);
          int s1i = __builtin_amdgcn_readlane(srcv, q*4+1);
          int s2i = __builtin_amdgcn_readlane(srcv, q*4+2);
          int s3i = __builtin_amdgcn_readlane(srcv, q*4+3);
          float2 h0 = *(const float2*)(h + (size_t)s0*EMBD + c2);
          float2 h1 = *(const float2*)(h + (size_t)s1i*EMBD + c2);
          float2 h2 = *(const float2*)(h + (size_t)s2i*EMBD + c2);
          float2 h3 = *(const float2*)(h + (size_t)s3i*EMBD + c2);
          float m1 = (q*4+1 < cnt) ? 1.f : 0.f;
          float m2 = (q*4+2 < cnt) ? 1.f : 0.f;
          float m3 = (q*4+3 < cnt) ? 1.f : 0.f;
          bx += h0.x; by += h0.y;
          bx = fmaf(m1, h1.x, bx); by = fmaf(m1, h1.y, by);
          bx = fmaf(m2, h2.x, bx); by = fmaf(m2, h2.y, by);
          bx = fmaf(m3, h3.x, bx); by = fmaf(m3, h3.y, by);
        }
      }
    }

    // reduce s1p across kb groups (rows live in lanes lr, lr+16, lr+32, lr+48)
    #pragma unroll
    for (int nf=0;nf<8;++nf){
      float v = s1p[nf];
      v += __shfl_xor(v, 16);
      v += __shfl_xor(v, 32);
      s1p[nf] = v;
    }
    // kb group g writes col tiles 2g, 2g+1 (static-index selects)
    float va = s1p[0], vb = s1p[1];
    if (kb == 1){ va = s1p[2]; vb = s1p[3]; }
    if (kb == 2){ va = s1p[4]; vb = s1p[5]; }
    if (kb == 3){ va = s1p[6]; vb = s1p[7]; }
    S1[(size_t)node*EMBD + kb*32 + lr]      = va;
    S1[(size_t)node*EMBD + kb*32 + 16 + lr] = vb;

    float deg = (float)(re - rs);
    float2 hn = *(const float2*)(h + (size_t)node*EMBD + c2);
    float ox = bx + hn.x + sfx + deg*eb2x;
    float oy = by + hn.y + sfy + deg*eb2y;
    *(float2*)(base + (size_t)node*EMBD + c2) = make_float2(ox, oy);
  }
}

// ------------- OLD edge kernel (ws-size fallback) -------------
__global__ __launch_bounds__(256) void k_edge(
    const float* __restrict__ h, const int* __restrict__ rowptr,
    const int* __restrict__ perm, const int* __restrict__ srcp,
    const float* __restrict__ edge_attr, const float* __restrict__ eaperm,
    const float* __restrict__ ew1l, const float* __restrict__ eb1l,
    const float* __restrict__ eb2l, const float* __restrict__ selfel,
    float* __restrict__ S1, float* __restrict__ base)
{
  __shared__ float w1s[EDIM*EMBD];
  __shared__ float b1s[EMBD];
  int tid = threadIdx.x;
  for (int i = tid; i < EDIM*EMBD; i += 256) w1s[i] = ew1l[i];
  if (tid < EMBD) b1s[tid] = eb1l[tid];
  __syncthreads();
  int lane = tid & 63;
  int node = blockIdx.x*4 + (tid >> 6);
  if (node >= NNODES) return;
  int rs = rowptr[node], re = rowptr[node+1];
  int c0 = lane*2;
  float s1x=0.f, s1y=0.f, bx=0.f, by=0.f;
  for (int i = rs; i < re; ++i){
    int s = __builtin_amdgcn_readfirstlane(srcp[i]);
    const float* ea;
    if (eaperm){
      ea = eaperm + (size_t)__builtin_amdgcn_readfirstlane(i)*EDIM;
    } else {
      ea = edge_attr + (size_t)__builtin_amdgcn_readfirstlane(perm[i])*EDIM;
    }
    float2 hs = *(const float2*)(h + (size_t)s*EMBD + c0);
    bx += hs.x; by += hs.y;
    float d0 = b1s[c0], d1 = b1s[c0+1];
    #pragma unroll
    for (int k=0;k<EDIM;++k){
      float av = ea[k];
      d0 += av * w1s[k*EMBD + c0];
      d1 += av * w1s[k*EMBD + c0 + 1];
    }
    s1x += leakyf(d0); s1y += leakyf(d1);
  }
  float deg = (float)(re - rs);
  float2 hv = *(const float2*)(h + (size_t)node*EMBD + c0);
  *(float2*)(S1 + (size_t)node*EMBD + c0) = make_float2(s1x, s1y);
  float bvx = bx + hv.x + selfel[c0]   + deg*eb2l[c0];
  float bvy = by + hv.y + selfel[c0+1] + deg*eb2l[c0+1];
  *(float2*)(base + (size_t)node*EMBD + c0) = make_float2(bvx, bvy);
}

// ------------- MFMA GEMM: C = act(A[M,K] @ B + bias), split-bf16 precision -------------
template<int BN, int WGM, int WGN, bool ALO, int ACT, bool STATS, bool OBF16, bool CONCAT, bool KCHK, bool ABF16>
__global__ __launch_bounds__(512) void k_mgemm(
    const float* __restrict__ Af, const float* __restrict__ A1,
    const __hip_bfloat16* __restrict__ Ab,
    int M, int Kreal, int Kpad, int lda,
    const __hip_bfloat16* __restrict__ Bp,
    const float* __restrict__ bias,
    float* __restrict__ Cf, __hip_bfloat16* __restrict__ Cb, int ldc,
    float* __restrict__ stats)
{
  static_assert(WGM*WGN == 8, "8 waves");
  constexpr int BM = 128;
  constexpr int MF = BM/(16*WGM);
  constexpr int NF = BN/(16*WGN);
  constexpr int LDS_ROW = 40;
  __shared__ __align__(16) unsigned short Ah[BM*LDS_ROW];
  __shared__ __align__(16) unsigned short Al[ALO ? BM*LDS_ROW : 8];
  __shared__ float ssum[STATS ? BN : 4];
  __shared__ float ssq [STATS ? BN : 4];

  int tid = threadIdx.x;
  int row0 = blockIdx.x*BM;
  int w = tid >> 6, lane = tid & 63;
  int wm = w / WGN, wn = w % WGN;
  int lr = lane & 15, kb = lane >> 4;
  int wrow = wm*MF*16, wcol = wn*NF*16;

  if (STATS && tid < BN){ ssum[tid] = 0.f; ssq[tid] = 0.f; }

  f32x4 acc[MF][NF];
  #pragma unroll
  for (int a=0;a<MF;++a)
    #pragma unroll
    for (int b=0;b<NF;++b) acc[a][b] = (f32x4)0.f;

  const size_t planeSz = (size_t)Kpad*BN;
  int sr = tid >> 2;
  int skq = (tid & 3)*8;
  int grow = row0 + sr;
  const int KS = Kpad >> 5;

  for (int ks = 0; ks < KS; ++ks){
    int k0 = ks << 5;
    int kg = k0 + skq;
    ushort8 hv, lv;
    if (ABF16){
      short8 raw = (short8)0;
      if (grow < M) raw = *reinterpret_cast<const short8*>((const unsigned short*)Ab + (size_t)grow*lda + kg);
      hv = *reinterpret_cast<ushort8*>(&raw);
    } else {
      float v[8];
      if (KCHK){
        #pragma unroll
        for (int i=0;i<8;++i)
          v[i] = (grow < M && kg+i < Kreal) ? Af[(size_t)grow*lda + kg + i] : 0.f;
      } else {
        const float* s;
        if (CONCAT) s = (kg < EMBD) ? (Af + (size_t)grow*lda + kg) : (A1 + (size_t)grow*lda + (kg - EMBD));
        else        s = Af + (size_t)grow*lda + kg;
        float4 p0 = make_float4(0,0,0,0), p1 = make_float4(0,0,0,0);
        if (grow < M){ p0 = *(const float4*)s; p1 = *(const float4*)(s+4); }
        v[0]=p0.x; v[1]=p0.y; v[2]=p0.z; v[3]=p0.w;
        v[4]=p1.x; v[5]=p1.y; v[6]=p1.z; v[7]=p1.w;
      }
      #pragma unroll
      for (int i=0;i<8;++i){
        unsigned short h16 = f2b(v[i]);
        hv[i] = h16;
        if (ALO) lv[i] = f2b(v[i] - b2f(h16));
      }
    }
    __syncthreads();
    *reinterpret_cast<ushort8*>(&Ah[sr*LDS_ROW + skq]) = hv;
    if (ALO && !ABF16) *reinterpret_cast<ushort8*>(&Al[sr*LDS_ROW + skq]) = lv;
    __syncthreads();

    short8 ah[MF], al[MF];
    #pragma unroll
    for (int mf=0; mf<MF; ++mf){
      int r = (wrow + mf*16 + lr)*LDS_ROW + kb*8;
      ah[mf] = *reinterpret_cast<const short8*>(&Ah[r]);
      if (ALO) al[mf] = *reinterpret_cast<const short8*>(&Al[r]);
    }
    const unsigned short* bb = (const unsigned short*)Bp + (size_t)ks*BN*32;
    short8 bh[NF], blv[NF];
    #pragma unroll
    for (int nf=0; nf<NF; ++nf){
      size_t off = (size_t)(wcol + nf*16 + lr)*32 + kb*8;
      bh[nf] = *reinterpret_cast<const short8*>(bb + off);
      blv[nf] = *reinterpret_cast<const short8*>(bb + planeSz + off);
    }
    #pragma unroll
    for (int mf=0; mf<MF; ++mf){
      #pragma unroll
      for (int nf=0; nf<NF; ++nf){
        acc[mf][nf] = __builtin_amdgcn_mfma_f32_16x16x32_bf16(ah[mf], bh[nf], acc[mf][nf], 0, 0, 0);
        acc[mf][nf] = __builtin_amdgcn_mfma_f32_16x16x32_bf16(ah[mf], blv[nf], acc[mf][nf], 0, 0, 0);
        if (ALO)
          acc[mf][nf] = __builtin_amdgcn_mfma_f32_16x16x32_bf16(al[mf], bh[nf], acc[mf][nf], 0, 0, 0);
      }
    }
  }

  float bcol[NF];
  #pragma unroll
  for (int nf=0; nf<NF; ++nf) bcol[nf] = bias ? bias[wcol + nf*16 + lr] : 0.f;
  float s[NF], sq[NF];
  #pragma unroll
  for (int nf=0; nf<NF; ++nf){ s[nf]=0.f; sq[nf]=0.f; }

  #pragma unroll
  for (int mf=0; mf<MF; ++mf){
    #pragma unroll
    for (int j=0; j<4; ++j){
      int r = row0 + wrow + mf*16 + kb*4 + j;
      if (r < M){
        #pragma unroll
        for (int nf=0; nf<NF; ++nf){
          int c = wcol + nf*16 + lr;
          float v = acc[mf][nf][j] + bcol[nf];
          if (ACT == 1) v = leakyf(v);
          if (ACT == 2) v = fmaxf(v, 0.f);
          if (OBF16) Cb[(size_t)r*ldc + c] = __float2bfloat16(v);
          else       Cf[(size_t)r*ldc + c] = v;
          if (STATS){ s[nf] += v; sq[nf] += v*v; }
        }
      }
    }
  }
  if (STATS){
    #pragma unroll
    for (int nf=0; nf<NF; ++nf){
      atomicAdd(&ssum[wcol + nf*16 + lr], s[nf]);
      atomicAdd(&ssq [wcol + nf*16 + lr], sq[nf]);
    }
    __syncthreads();
    if (tid < BN){
      atomicAdd(&stats[tid], ssum[tid]);
      atomicAdd(&stats[BN + tid], ssq[tid]);
    }
  }
}

// ------------- BatchNorm normalize (+optional relu) -------------
__global__ __launch_bounds__(256) void k_bn(const float* __restrict__ hh, const float* __restrict__ stats,
                                            const float* __restrict__ gamma, const float* __restrict__ beta,
                                            float* __restrict__ out, int dorelu){
  int idx = blockIdx.x*256 + threadIdx.x;
  if (idx >= NNODES*(EMBD/4)) return;
  int c0 = (idx & (EMBD/4 - 1)) * 4;
  float4 v = *(const float4*)(hh + (size_t)idx*4);
  float o[4] = {v.x, v.y, v.z, v.w};
  const float invN = 1.f / (float)NNODES;
  #pragma unroll
  for (int i=0;i<4;++i){
    int c = c0 + i;
    float mean = stats[c] * invN;
    float var  = stats[EMBD + c] * invN - mean*mean;
    float inv  = rsqrtf(fmaxf(var, 0.f) + BNEPS);
    float y = (o[i] - mean) * inv * gamma[c] + beta[c];
    if (dorelu) y = fmaxf(y, 0.f);
    o[i] = y;
  }
  *(float4*)(out + (size_t)idx*4) = make_float4(o[0],o[1],o[2],o[3]);
}

// ---------------- launcher ----------------
extern "C" void kernel_launch(void* const* d_in, const int* in_sizes, int n_in,
                              void* d_out, int out_size, void* d_ws, size_t ws_size,
                              hipStream_t stream)
{
  const float* x   = (const float*)d_in[0];
  const float* ea  = (const float*)d_in[1];
  const float* iw1 = (const float*)d_in[2];
  const float* ib1 = (const float*)d_in[3];
  const float* iw2 = (const float*)d_in[4];
  const float* ib2 = (const float*)d_in[5];
  const float* ew1 = (const float*)d_in[6];
  const float* eb1 = (const float*)d_in[7];
  const float* ew2 = (const float*)d_in[8];
  const float* eb2 = (const float*)d_in[9];
  const float* mw1 = (const float*)d_in[10];
  const float* mb1 = (const float*)d_in[11];
  const float* mw2 = (const float*)d_in[12];
  const float* mb2 = (const float*)d_in[13];
  const float* gamma = (const float*)d_in[14];
  const float* beta  = (const float*)d_in[15];
  const int* eidx = (const int*)d_in[16];
  const int* srcI = eidx;
  const int* dstI = eidx + NEDGES;

  char* p = (char*)d_ws;
  auto alloc = [&](size_t bytes)->char*{
    char* r = p; p += (bytes + 255) & ~(size_t)255; return r;
  };
  float* hbuf  = (float*)alloc((size_t)NNODES*EMBD*4);
  float* S1    = (float*)alloc((size_t)NNODES*EMBD*4);
  float* base  = (float*)alloc((size_t)NNODES*EMBD*4);
  __hip_bfloat16* tbuf = (__hip_bfloat16*)alloc((size_t)NNODES*2*EMBD*2);
  int* perm   = (int*)alloc((size_t)NEDGES*4);
  int* srcp   = (int*)alloc((size_t)NEDGES*4);
  int* rowptr = (int*)alloc((size_t)(NNODES+1)*4);
  int* cursor = (int*)alloc((size_t)NNODES*4);
  int* bsum   = (int*)alloc(4096);
  int* boff   = (int*)alloc(4096);
  float* selfe = (float*)alloc(NLAYER*EMBD*4);
  float* stats = (float*)alloc(2*EMBD*4);
  float* wc    = (float*)alloc((size_t)NLAYER*EMBD*2*EMBD*4);
  __hip_bfloat16* Bi1 = (__hip_bfloat16*)alloc((size_t)192*EMBD*2*2);
  __hip_bfloat16* Bi2 = (__hip_bfloat16*)alloc((size_t)EMBD*EMBD*2*2);
  __hip_bfloat16* B1  = (__hip_bfloat16*)alloc((size_t)NLAYER*256*256*2*2);
  __hip_bfloat16* B2  = (__hip_bfloat16*)alloc((size_t)NLAYER*256*EMBD*2*2);
  size_t used = (size_t)(p - (char*)d_ws);

  bool use_new = (ws_size >= used + (size_t)NEDGES*24*2 + 256);
  unsigned short* eap24 = nullptr;
  float* eaperm = nullptr;
  if (use_new) eap24 = (unsigned short*)alloc((size_t)NEDGES*24*2);
  else if (ws_size >= used + (size_t)NEDGES*EDIM*4 + 256)
    eaperm = (float*)alloc((size_t)NEDGES*EDIM*4);

  // ---- CSR build ----
  hipMemsetAsync(cursor, 0, (size_t)NNODES*4, stream);
  k_hist<<<(NEDGES+255)/256, 256, 0, stream>>>(dstI, cursor);
  int nb = (NNODES+255)/256;
  k_scan1<<<nb, 256, 0, stream>>>(cursor, rowptr, bsum);
  k_scan2<<<1, 512, 0, stream>>>(bsum, boff, nb);
  k_scan3<<<(NNODES+255)/256, 256, 0, stream>>>(rowptr, boff);
  k_curcopy<<<(NNODES+255)/256, 256, 0, stream>>>(rowptr, cursor);
  if (use_new)
    k_fill_new<<<(NEDGES+255)/256, 256, 0, stream>>>(srcI, dstI, ea, cursor, srcp, eap24);
  else
    k_fill<<<(NEDGES+255)/256, 256, 0, stream>>>(srcI, dstI, ea, cursor, perm, srcp, eaperm);
  k_selfe<<<NLAYER, EMBD, 0, stream>>>(eb1, ew2, eb2, selfe);

  // ---- weight prep ----
  k_wc<<<(NLAYER*EMBD*2*EMBD)/256, 256, 0, stream>>>(ew2, mw1, wc);
  k_pack<<<(192*EMBD+255)/256, 256, 0, stream>>>(iw1, XDIM, iw1, XDIM, 192, EMBD, Bi1);
  k_pack<<<(EMBD*EMBD+255)/256, 256, 0, stream>>>(iw2, EMBD, iw2, EMBD, EMBD, EMBD, Bi2);
  for (int l=0; l<NLAYER; ++l){
    k_pack<<<(256*256+255)/256, 256, 0, stream>>>(
        wc + (size_t)l*EMBD*2*EMBD, EMBD, mw1 + (size_t)l*EMBD*2*EMBD, 256, 256, 256,
        B1 + (size_t)l*256*256*2);
    k_pack<<<(256*EMBD+255)/256, 256, 0, stream>>>(
        mw2 + (size_t)l*2*EMBD*EMBD, 256, mw2, 256, 256, EMBD,
        B2 + (size_t)l*256*EMBD*2);
  }

  const int gx = (NNODES + 127)/128;

  // ---- input MLP ----
  k_mgemm<128,4,2, true,1,false,false,false,true ,false><<<gx, 512, 0, stream>>>(
      x, nullptr, nullptr, NNODES, XDIM, 192, XDIM, Bi1, ib1, S1, nullptr, EMBD, nullptr);
  k_mgemm<128,4,2, true,0,false,false,false,false,false><<<gx, 512, 0, stream>>>(
      S1, nullptr, nullptr, NNODES, EMBD, EMBD, EMBD, Bi2, ib2, hbuf, nullptr, EMBD, nullptr);

  for (int l=0; l<NLAYER; ++l){
    hipMemsetAsync(stats, 0, 2*EMBD*4, stream);
    if (use_new)
      k_edge_mfma<<<2048, 256, 0, stream>>>(
          hbuf, rowptr, srcp, eap24,
          ew1 + (size_t)l*EDIM*EMBD, eb1 + l*EMBD, eb2 + l*EMBD, selfe + l*EMBD,
          S1, base);
    else
      k_edge<<<NNODES/4, 256, 0, stream>>>(
          hbuf, rowptr, perm, srcp, ea, eaperm,
          ew1 + (size_t)l*EDIM*EMBD, eb1 + l*EMBD, eb2 + l*EMBD, selfe + l*EMBD,
          S1, base);
    // t = relu([S1|base] @ [Wc;mw1] + mb1)  -> bf16 [N,256]
    k_mgemm<256,2,4, true,2,false,true ,true ,false,false><<<gx, 512, 0, stream>>>(
        S1, base, nullptr, NNODES, 256, 256, EMBD, B1 + (size_t)l*256*256*2,
        mb1 + l*2*EMBD, nullptr, tbuf, 2*EMBD, nullptr);
    // hh (into S1) = t @ mw2 + mb2, fused BN stats
    k_mgemm<128,4,2, false,0,true ,false,false,false,true ><<<gx, 512, 0, stream>>>(
        nullptr, nullptr, tbuf, NNODES, 256, 256, 2*EMBD, B2 + (size_t)l*256*EMBD*2,
        mb2 + l*EMBD, S1, nullptr, EMBD, stats);
    float* outp = (l == NLAYER-1) ? (float*)d_out : hbuf;
    k_bn<<<(NNODES*(EMBD/4)+255)/256, 256, 0, stream>>>(
        S1, stats, gamma + l*EMBD, beta + l*EMBD, outp, (l < NLAYER-1) ? 1 : 0);
  }
}

// Round 4
// 2078.464 us; speedup vs baseline: 2.3042x; 1.0099x over previous
//
#include <hip/hip_runtime.h>
#include <hip/hip_bf16.h>
#include <cstdint>
#include <cstddef>

#define NNODES 100000
#define NEDGES 1600000
#define EMBD 128
#define NLAYER 5
#define XDIM 178
#define EDIM 18
#define BNEPS 1e-5f

typedef __attribute__((ext_vector_type(8))) short short8;
typedef __attribute__((ext_vector_type(8))) unsigned short ushort8;
typedef __attribute__((ext_vector_type(4))) float f32x4;

static __device__ __forceinline__ float leakyf(float v){ return v > 0.f ? v : 0.1f*v; }
static __device__ __forceinline__ unsigned short f2b(float v){
  __hip_bfloat16 b = __float2bfloat16(v);
  return *reinterpret_cast<unsigned short*>(&b);
}
static __device__ __forceinline__ float b2f(unsigned short u){
  __hip_bfloat16 b = *reinterpret_cast<__hip_bfloat16*>(&u);
  return __bfloat162float(b);
}

// ---------------- CSR build ----------------
__global__ __launch_bounds__(256) void k_hist(const int* __restrict__ dst, int* __restrict__ cnt){
  int e = blockIdx.x*256 + threadIdx.x;
  if (e < NEDGES) atomicAdd(&cnt[dst[e]], 1);
}

__global__ __launch_bounds__(256) void k_scan1(const int* __restrict__ cnt, int* __restrict__ rowptr,
                                               int* __restrict__ bsum){
  __shared__ int s[256];
  int t = threadIdx.x, i = blockIdx.x*256 + t;
  int v = (i < NNODES) ? cnt[i] : 0;
  s[t] = v; __syncthreads();
  for (int off=1; off<256; off<<=1){
    int x = (t>=off) ? s[t-off] : 0; __syncthreads();
    s[t] += x; __syncthreads();
  }
  if (i < NNODES) rowptr[i+1] = s[t];
  if (t == 255) bsum[blockIdx.x] = s[t];
}

__global__ __launch_bounds__(512) void k_scan2(const int* __restrict__ bsum, int* __restrict__ boff, int nb){
  __shared__ int s[512];
  int t = threadIdx.x;
  int v = (t < nb) ? bsum[t] : 0;
  s[t] = v; __syncthreads();
  for (int off=1; off<512; off<<=1){
    int x = (t>=off) ? s[t-off] : 0; __syncthreads();
    s[t] += x; __syncthreads();
  }
  if (t < nb) boff[t] = s[t] - v;
}

__global__ __launch_bounds__(256) void k_scan3(int* __restrict__ rowptr, const int* __restrict__ boff){
  int i = blockIdx.x*256 + threadIdx.x;
  if (i < NNODES) rowptr[i+1] += boff[i>>8];
  if (i == 0) rowptr[0] = 0;
}

__global__ __launch_bounds__(256) void k_curcopy(const int* __restrict__ rowptr, int* __restrict__ cursor){
  int i = blockIdx.x*256 + threadIdx.x;
  if (i < NNODES) cursor[i] = rowptr[i];
}

// new-path fill: srcp + bf16-packed ea rows (24 shorts: 18 attrs, slot18=1.0, rest 0)
__global__ __launch_bounds__(256) void k_fill_new(const int* __restrict__ src, const int* __restrict__ dst,
                                                  const float* __restrict__ ea, int* __restrict__ cursor,
                                                  int* __restrict__ srcp, unsigned short* __restrict__ eap24){
  int e = blockIdx.x*256 + threadIdx.x;
  if (e >= NEDGES) return;
  int pos = atomicAdd(&cursor[dst[e]], 1);
  srcp[pos] = src[e];
  const float* a = ea + (size_t)e*EDIM;
  ushort8 r0, r1, r2;
  #pragma unroll
  for (int k=0;k<8;++k)  r0[k] = f2b(a[k]);
  #pragma unroll
  for (int k=0;k<8;++k)  r1[k] = f2b(a[8+k]);
  #pragma unroll
  for (int k=0;k<8;++k)  r2[k] = 0;
  r2[0] = f2b(a[16]); r2[1] = f2b(a[17]);
  r2[2] = 0x3F80;   // bf16 1.0 at k=18 -> bias slot
  unsigned short* o = eap24 + (size_t)pos*24;
  *reinterpret_cast<ushort8*>(o)      = r0;
  *reinterpret_cast<ushort8*>(o + 8)  = r1;
  *reinterpret_cast<ushort8*>(o + 16) = r2;
}

// old-path fill (fallback)
__global__ __launch_bounds__(256) void k_fill(const int* __restrict__ src, const int* __restrict__ dst,
                                              const float* __restrict__ ea, int* __restrict__ cursor,
                                              int* __restrict__ perm, int* __restrict__ srcp,
                                              float* __restrict__ eap){
  int e = blockIdx.x*256 + threadIdx.x;
  if (e >= NEDGES) return;
  int pos = atomicAdd(&cursor[dst[e]], 1);
  perm[pos] = e;
  srcp[pos] = src[e];
  if (eap){
    const float* a = ea + (size_t)e*EDIM;
    float* o = eap + (size_t)pos*EDIM;
    #pragma unroll
    for (int k=0;k<EDIM;++k) o[k] = a[k];
  }
}

// self_e[l] = leaky(eb1[l]) @ ew2[l] + eb2[l]
__global__ __launch_bounds__(128) void k_selfe(const float* __restrict__ eb1, const float* __restrict__ ew2,
                                               const float* __restrict__ eb2, float* __restrict__ selfe){
  int l = blockIdx.x, c = threadIdx.x;
  const float* b1 = eb1 + l*EMBD;
  const float* w2 = ew2 + (size_t)l*EMBD*EMBD;
  float acc = eb2[l*EMBD + c];
  for (int j=0;j<EMBD;++j) acc += leakyf(b1[j]) * w2[j*EMBD + c];
  selfe[l*EMBD + c] = acc;
}

// Wc[l] = ew2[l] @ mw1[l]  ([128][256] fp32)
__global__ __launch_bounds__(256) void k_wc(const float* __restrict__ ew2, const float* __restrict__ mw1,
                                            float* __restrict__ wc){
  int idx = blockIdx.x*256 + threadIdx.x;       // 5*128*256
  int l = idx >> 15, rem = idx & 32767;
  int i = rem >> 8, n = rem & 255;
  const float* e = ew2 + (size_t)l*EMBD*EMBD + i*EMBD;
  const float* m = mw1 + (size_t)l*EMBD*2*EMBD + n;
  float acc = 0.f;
  #pragma unroll 4
  for (int j=0;j<EMBD;++j) acc += e[j]*m[(size_t)j*2*EMBD];
  wc[idx] = acc;
}

// pack B [Kpad x N] into hi/lo bf16 planes laid out [ks][n][kk]
__global__ __launch_bounds__(256) void k_pack(const float* __restrict__ s1, int rows1,
                                              const float* __restrict__ s2, int Kreal,
                                              int Kpad, int N, __hip_bfloat16* __restrict__ out){
  int idx = blockIdx.x*256 + threadIdx.x;
  if (idx >= Kpad*N) return;
  int k = idx / N, n = idx - k*N;
  float v = 0.f;
  if (k < rows1) v = s1[(size_t)k*N + n];
  else if (k < Kreal) v = s2[(size_t)(k-rows1)*N + n];
  unsigned short hi = f2b(v);
  unsigned short lo = f2b(v - b2f(hi));
  size_t o = (size_t)(k>>5)*N*32 + (size_t)n*32 + (k&31);
  unsigned short* po = (unsigned short*)out;
  po[o] = hi;
  po[(size_t)Kpad*N + o] = lo;
}

// ------------- edge kernel v3: MFMA edge-MLP + 2-edge-interleaved float4 gather -------------
// One wave per node (persistent). Chunk = 16 edges.
// MFMA A[16x32]: rows=edges, k=0..17 ea(bf16), k=18 const 1 (bias). B = ew1/eb1 split hi/lo in regs.
// Gather: lanes 0-31 handle even edge of a pair, lanes 32-63 odd edge; float4 per lane.
__global__ __launch_bounds__(256) void k_edge_mfma(
    const float* __restrict__ h, const int* __restrict__ rowptr,
    const int* __restrict__ srcp, const unsigned short* __restrict__ eap24,
    const float* __restrict__ ew1l, const float* __restrict__ eb1l,
    const float* __restrict__ eb2l, const float* __restrict__ selfel,
    float* __restrict__ S1, float* __restrict__ base)
{
  int tid = threadIdx.x;
  int lane = tid & 63;
  int lr = lane & 15, kb = lane >> 4;
  int half = lane >> 5, li = lane & 31;
  int c4 = li*4;

  // B fragments once per wave: col = nf*16+lr, k = kb*8+j
  short8 bh[8], bl[8];
  #pragma unroll
  for (int nf=0; nf<8; ++nf){
    int col = nf*16 + lr;
    ushort8 hh8, ll8;
    #pragma unroll
    for (int j=0;j<8;++j){
      int k = kb*8 + j;
      float v = 0.f;
      if (k < EDIM) v = ew1l[k*EMBD + col];
      else if (k == EDIM) v = eb1l[col];
      unsigned short hi = f2b(v);
      hh8[j] = hi;
      ll8[j] = f2b(v - b2f(hi));
    }
    bh[nf] = *reinterpret_cast<short8*>(&hh8);
    bl[nf] = *reinterpret_cast<short8*>(&ll8);
  }
  float4 sf4 = *(const float4*)(selfel + c4);
  float4 e24 = *(const float4*)(eb2l + c4);

  int wid = blockIdx.x*4 + (tid>>6);
  const int NW = gridDim.x*4;
  for (int node = wid; node < NNODES; node += NW){
    int rs = rowptr[node], re = rowptr[node+1];
    float s1p[8];
    #pragma unroll
    for (int nf=0;nf<8;++nf) s1p[nf]=0.f;
    f32x4 bacc = (f32x4)0.f;

    for (int c0 = rs; c0 < re; c0 += 16){
      int cnt = re - c0;                       // wave-uniform

      // ---- h gather: 8 pairs, 2 edges per instruction, float4 lanes ----
      #pragma unroll
      for (int p=0;p<8;++p){
        int r = 2*p + half;
        int e = c0 + r; if (e > re-1) e = re-1;
        float m = (r < cnt) ? 1.f : 0.f;
        int sp = srcp[e];
        float4 hv = *(const float4*)(h + (size_t)sp*EMBD + c4);
        bacc[0] = fmaf(m, hv.x, bacc[0]);
        bacc[1] = fmaf(m, hv.y, bacc[1]);
        bacc[2] = fmaf(m, hv.z, bacc[2]);
        bacc[3] = fmaf(m, hv.w, bacc[3]);
      }

      // ---- edge MLP via MFMA ----
      int idx = c0 + lr; if (idx > re-1) idx = re-1;
      short8 af = (short8)0;
      if (kb < 3){
        ushort8 t = *reinterpret_cast<const ushort8*>(eap24 + (size_t)idx*24 + kb*8);
        af = *reinterpret_cast<short8*>(&t);
      }
      if (lr >= cnt) af = (short8)0;
      #pragma unroll
      for (int nf=0;nf<8;++nf){
        f32x4 acc = (f32x4)0.f;
        acc = __builtin_amdgcn_mfma_f32_16x16x32_bf16(af, bl[nf], acc, 0,0,0);
        acc = __builtin_amdgcn_mfma_f32_16x16x32_bf16(af, bh[nf], acc, 0,0,0);
        #pragma unroll
        for (int j=0;j<4;++j){
          float v = acc[j];                    // leaky(v) = 0.55v + 0.45|v|
          s1p[nf] = fmaf(0.55f, v, s1p[nf]);
          s1p[nf] = fmaf(0.45f, fabsf(v), s1p[nf]);
        }
      }
    }

    // reduce s1p across kb groups (rows live in lanes lr, lr+16, lr+32, lr+48)
    #pragma unroll
    for (int nf=0;nf<8;++nf){
      float v = s1p[nf];
      v += __shfl_xor(v, 16);
      v += __shfl_xor(v, 32);
      s1p[nf] = v;
    }
    float va = s1p[0], vb = s1p[1];
    if (kb == 1){ va = s1p[2]; vb = s1p[3]; }
    if (kb == 2){ va = s1p[4]; vb = s1p[5]; }
    if (kb == 3){ va = s1p[6]; vb = s1p[7]; }
    S1[(size_t)node*EMBD + kb*32 + lr]      = va;
    S1[(size_t)node*EMBD + kb*32 + 16 + lr] = vb;

    // fold gather halves: every lane gets even+odd sum for its 4 columns
    #pragma unroll
    for (int j=0;j<4;++j) bacc[j] += __shfl_xor(bacc[j], 32);

    if (half == 0){
      float deg = (float)(re - rs);
      float4 hn = *(const float4*)(h + (size_t)node*EMBD + c4);
      float4 o;
      o.x = bacc[0] + hn.x + sf4.x + deg*e24.x;
      o.y = bacc[1] + hn.y + sf4.y + deg*e24.y;
      o.z = bacc[2] + hn.z + sf4.z + deg*e24.z;
      o.w = bacc[3] + hn.w + sf4.w + deg*e24.w;
      *(float4*)(base + (size_t)node*EMBD + c4) = o;
    }
  }
}

// ------------- OLD edge kernel (ws-size fallback) -------------
__global__ __launch_bounds__(256) void k_edge(
    const float* __restrict__ h, const int* __restrict__ rowptr,
    const int* __restrict__ perm, const int* __restrict__ srcp,
    const float* __restrict__ edge_attr, const float* __restrict__ eaperm,
    const float* __restrict__ ew1l, const float* __restrict__ eb1l,
    const float* __restrict__ eb2l, const float* __restrict__ selfel,
    float* __restrict__ S1, float* __restrict__ base)
{
  __shared__ float w1s[EDIM*EMBD];
  __shared__ float b1s[EMBD];
  int tid = threadIdx.x;
  for (int i = tid; i < EDIM*EMBD; i += 256) w1s[i] = ew1l[i];
  if (tid < EMBD) b1s[tid] = eb1l[tid];
  __syncthreads();
  int lane = tid & 63;
  int node = blockIdx.x*4 + (tid >> 6);
  if (node >= NNODES) return;
  int rs = rowptr[node], re = rowptr[node+1];
  int c0 = lane*2;
  float s1x=0.f, s1y=0.f, bx=0.f, by=0.f;
  for (int i = rs; i < re; ++i){
    int s = __builtin_amdgcn_readfirstlane(srcp[i]);
    const float* ea;
    if (eaperm){
      ea = eaperm + (size_t)__builtin_amdgcn_readfirstlane(i)*EDIM;
    } else {
      ea = edge_attr + (size_t)__builtin_amdgcn_readfirstlane(perm[i])*EDIM;
    }
    float2 hs = *(const float2*)(h + (size_t)s*EMBD + c0);
    bx += hs.x; by += hs.y;
    float d0 = b1s[c0], d1 = b1s[c0+1];
    #pragma unroll
    for (int k=0;k<EDIM;++k){
      float av = ea[k];
      d0 += av * w1s[k*EMBD + c0];
      d1 += av * w1s[k*EMBD + c0 + 1];
    }
    s1x += leakyf(d0); s1y += leakyf(d1);
  }
  float deg = (float)(re - rs);
  float2 hv = *(const float2*)(h + (size_t)node*EMBD + c0);
  *(float2*)(S1 + (size_t)node*EMBD + c0) = make_float2(s1x, s1y);
  float bvx = bx + hv.x + selfel[c0]   + deg*eb2l[c0];
  float bvy = by + hv.y + selfel[c0+1] + deg*eb2l[c0+1];
  *(float2*)(base + (size_t)node*EMBD + c0) = make_float2(bvx, bvy);
}

// ------------- MFMA GEMM: C = act(A[M,K] @ B + bias), split-bf16 precision -------------
template<int BN, int WGM, int WGN, bool ALO, int ACT, bool STATS, bool OBF16, bool CONCAT, bool KCHK, bool ABF16>
__global__ __launch_bounds__(512) void k_mgemm(
    const float* __restrict__ Af, const float* __restrict__ A1,
    const __hip_bfloat16* __restrict__ Ab,
    int M, int Kreal, int Kpad, int lda,
    const __hip_bfloat16* __restrict__ Bp,
    const float* __restrict__ bias,
    float* __restrict__ Cf, __hip_bfloat16* __restrict__ Cb, int ldc,
    float* __restrict__ stats)
{
  static_assert(WGM*WGN == 8, "8 waves");
  constexpr int BM = 128;
  constexpr int MF = BM/(16*WGM);
  constexpr int NF = BN/(16*WGN);
  constexpr int LDS_ROW = 40;
  __shared__ __align__(16) unsigned short Ah[BM*LDS_ROW];
  __shared__ __align__(16) unsigned short Al[ALO ? BM*LDS_ROW : 8];
  __shared__ float ssum[STATS ? BN : 4];
  __shared__ float ssq [STATS ? BN : 4];

  int tid = threadIdx.x;
  int row0 = blockIdx.x*BM;
  int w = tid >> 6, lane = tid & 63;
  int wm = w / WGN, wn = w % WGN;
  int lr = lane & 15, kb = lane >> 4;
  int wrow = wm*MF*16, wcol = wn*NF*16;

  if (STATS && tid < BN){ ssum[tid] = 0.f; ssq[tid] = 0.f; }

  f32x4 acc[MF][NF];
  #pragma unroll
  for (int a=0;a<MF;++a)
    #pragma unroll
    for (int b=0;b<NF;++b) acc[a][b] = (f32x4)0.f;

  const size_t planeSz = (size_t)Kpad*BN;
  int sr = tid >> 2;
  int skq = (tid & 3)*8;
  int grow = row0 + sr;
  const int KS = Kpad >> 5;

  for (int ks = 0; ks < KS; ++ks){
    int k0 = ks << 5;
    int kg = k0 + skq;
    ushort8 hv, lv;
    if (ABF16){
      short8 raw = (short8)0;
      if (grow < M) raw = *reinterpret_cast<const short8*>((const unsigned short*)Ab + (size_t)grow*lda + kg);
      hv = *reinterpret_cast<ushort8*>(&raw);
    } else {
      float v[8];
      if (KCHK){
        #pragma unroll
        for (int i=0;i<8;++i)
          v[i] = (grow < M && kg+i < Kreal) ? Af[(size_t)grow*lda + kg + i] : 0.f;
      } else {
        const float* s;
        if (CONCAT) s = (kg < EMBD) ? (Af + (size_t)grow*lda + kg) : (A1 + (size_t)grow*lda + (kg - EMBD));
        else        s = Af + (size_t)grow*lda + kg;
        float4 p0 = make_float4(0,0,0,0), p1 = make_float4(0,0,0,0);
        if (grow < M){ p0 = *(const float4*)s; p1 = *(const float4*)(s+4); }
        v[0]=p0.x; v[1]=p0.y; v[2]=p0.z; v[3]=p0.w;
        v[4]=p1.x; v[5]=p1.y; v[6]=p1.z; v[7]=p1.w;
      }
      #pragma unroll
      for (int i=0;i<8;++i){
        unsigned short h16 = f2b(v[i]);
        hv[i] = h16;
        if (ALO) lv[i] = f2b(v[i] - b2f(h16));
      }
    }
    __syncthreads();
    *reinterpret_cast<ushort8*>(&Ah[sr*LDS_ROW + skq]) = hv;
    if (ALO && !ABF16) *reinterpret_cast<ushort8*>(&Al[sr*LDS_ROW + skq]) = lv;
    __syncthreads();

    short8 ah[MF], al[MF];
    #pragma unroll
    for (int mf=0; mf<MF; ++mf){
      int r = (wrow + mf*16 + lr)*LDS_ROW + kb*8;
      ah[mf] = *reinterpret_cast<const short8*>(&Ah[r]);
      if (ALO) al[mf] = *reinterpret_cast<const short8*>(&Al[r]);
    }
    const unsigned short* bb = (const unsigned short*)Bp + (size_t)ks*BN*32;
    short8 bh[NF], blv[NF];
    #pragma unroll
    for (int nf=0; nf<NF; ++nf){
      size_t off = (size_t)(wcol + nf*16 + lr)*32 + kb*8;
      bh[nf] = *reinterpret_cast<const short8*>(bb + off);
      blv[nf] = *reinterpret_cast<const short8*>(bb + planeSz + off);
    }
    #pragma unroll
    for (int mf=0; mf<MF; ++mf){
      #pragma unroll
      for (int nf=0; nf<NF; ++nf){
        acc[mf][nf] = __builtin_amdgcn_mfma_f32_16x16x32_bf16(ah[mf], bh[nf], acc[mf][nf], 0, 0, 0);
        acc[mf][nf] = __builtin_amdgcn_mfma_f32_16x16x32_bf16(ah[mf], blv[nf], acc[mf][nf], 0, 0, 0);
        if (ALO)
          acc[mf][nf] = __builtin_amdgcn_mfma_f32_16x16x32_bf16(al[mf], bh[nf], acc[mf][nf], 0, 0, 0);
      }
    }
  }

  float bcol[NF];
  #pragma unroll
  for (int nf=0; nf<NF; ++nf) bcol[nf] = bias ? bias[wcol + nf*16 + lr] : 0.f;
  float s[NF], sq[NF];
  #pragma unroll
  for (int nf=0; nf<NF; ++nf){ s[nf]=0.f; sq[nf]=0.f; }

  #pragma unroll
  for (int mf=0; mf<MF; ++mf){
    #pragma unroll
    for (int j=0; j<4; ++j){
      int r = row0 + wrow + mf*16 + kb*4 + j;
      if (r < M){
        #pragma unroll
        for (int nf=0; nf<NF; ++nf){
          int c = wcol + nf*16 + lr;
          float v = acc[mf][nf][j] + bcol[nf];
          if (ACT == 1) v = leakyf(v);
          if (ACT == 2) v = fmaxf(v, 0.f);
          if (OBF16) Cb[(size_t)r*ldc + c] = __float2bfloat16(v);
          else       Cf[(size_t)r*ldc + c] = v;
          if (STATS){ s[nf] += v; sq[nf] += v*v; }
        }
      }
    }
  }
  if (STATS){
    #pragma unroll
    for (int nf=0; nf<NF; ++nf){
      atomicAdd(&ssum[wcol + nf*16 + lr], s[nf]);
      atomicAdd(&ssq [wcol + nf*16 + lr], sq[nf]);
    }
    __syncthreads();
    if (tid < BN){
      atomicAdd(&stats[tid], ssum[tid]);
      atomicAdd(&stats[BN + tid], ssq[tid]);
    }
  }
}

// ------------- BatchNorm normalize (+optional relu) -------------
__global__ __launch_bounds__(256) void k_bn(const float* __restrict__ hh, const float* __restrict__ stats,
                                            const float* __restrict__ gamma, const float* __restrict__ beta,
                                            float* __restrict__ out, int dorelu){
  int idx = blockIdx.x*256 + threadIdx.x;
  if (idx >= NNODES*(EMBD/4)) return;
  int c0 = (idx & (EMBD/4 - 1)) * 4;
  float4 v = *(const float4*)(hh + (size_t)idx*4);
  float o[4] = {v.x, v.y, v.z, v.w};
  const float invN = 1.f / (float)NNODES;
  #pragma unroll
  for (int i=0;i<4;++i){
    int c = c0 + i;
    float mean = stats[c] * invN;
    float var  = stats[EMBD + c] * invN - mean*mean;
    float inv  = rsqrtf(fmaxf(var, 0.f) + BNEPS);
    float y = (o[i] - mean) * inv * gamma[c] + beta[c];
    if (dorelu) y = fmaxf(y, 0.f);
    o[i] = y;
  }
  *(float4*)(out + (size_t)idx*4) = make_float4(o[0],o[1],o[2],o[3]);
}

// ---------------- launcher ----------------
extern "C" void kernel_launch(void* const* d_in, const int* in_sizes, int n_in,
                              void* d_out, int out_size, void* d_ws, size_t ws_size,
                              hipStream_t stream)
{
  const float* x   = (const float*)d_in[0];
  const float* ea  = (const float*)d_in[1];
  const float* iw1 = (const float*)d_in[2];
  const float* ib1 = (const float*)d_in[3];
  const float* iw2 = (const float*)d_in[4];
  const float* ib2 = (const float*)d_in[5];
  const float* ew1 = (const float*)d_in[6];
  const float* eb1 = (const float*)d_in[7];
  const float* ew2 = (const float*)d_in[8];
  const float* eb2 = (const float*)d_in[9];
  const float* mw1 = (const float*)d_in[10];
  const float* mb1 = (const float*)d_in[11];
  const float* mw2 = (const float*)d_in[12];
  const float* mb2 = (const float*)d_in[13];
  const float* gamma = (const float*)d_in[14];
  const float* beta  = (const float*)d_in[15];
  const int* eidx = (const int*)d_in[16];
  const int* srcI = eidx;
  const int* dstI = eidx + NEDGES;

  char* p = (char*)d_ws;
  auto alloc = [&](size_t bytes)->char*{
    char* r = p; p += (bytes + 255) & ~(size_t)255; return r;
  };
  float* hbuf  = (float*)alloc((size_t)NNODES*EMBD*4);
  float* S1    = (float*)alloc((size_t)NNODES*EMBD*4);
  float* base  = (float*)alloc((size_t)NNODES*EMBD*4);
  __hip_bfloat16* tbuf = (__hip_bfloat16*)alloc((size_t)NNODES*2*EMBD*2);
  int* perm   = (int*)alloc((size_t)NEDGES*4);
  int* srcp   = (int*)alloc((size_t)NEDGES*4);
  int* rowptr = (int*)alloc((size_t)(NNODES+1)*4);
  int* cursor = (int*)alloc((size_t)NNODES*4);
  int* bsum   = (int*)alloc(4096);
  int* boff   = (int*)alloc(4096);
  float* selfe = (float*)alloc(NLAYER*EMBD*4);
  float* stats = (float*)alloc(2*EMBD*4);
  float* wc    = (float*)alloc((size_t)NLAYER*EMBD*2*EMBD*4);
  __hip_bfloat16* Bi1 = (__hip_bfloat16*)alloc((size_t)192*EMBD*2*2);
  __hip_bfloat16* Bi2 = (__hip_bfloat16*)alloc((size_t)EMBD*EMBD*2*2);
  __hip_bfloat16* B1  = (__hip_bfloat16*)alloc((size_t)NLAYER*256*256*2*2);
  __hip_bfloat16* B2  = (__hip_bfloat16*)alloc((size_t)NLAYER*256*EMBD*2*2);
  size_t used = (size_t)(p - (char*)d_ws);

  bool use_new = (ws_size >= used + (size_t)NEDGES*24*2 + 256);
  unsigned short* eap24 = nullptr;
  float* eaperm = nullptr;
  if (use_new) eap24 = (unsigned short*)alloc((size_t)NEDGES*24*2);
  else if (ws_size >= used + (size_t)NEDGES*EDIM*4 + 256)
    eaperm = (float*)alloc((size_t)NEDGES*EDIM*4);

  // ---- CSR build ----
  hipMemsetAsync(cursor, 0, (size_t)NNODES*4, stream);
  k_hist<<<(NEDGES+255)/256, 256, 0, stream>>>(dstI, cursor);
  int nb = (NNODES+255)/256;
  k_scan1<<<nb, 256, 0, stream>>>(cursor, rowptr, bsum);
  k_scan2<<<1, 512, 0, stream>>>(bsum, boff, nb);
  k_scan3<<<(NNODES+255)/256, 256, 0, stream>>>(rowptr, boff);
  k_curcopy<<<(NNODES+255)/256, 256, 0, stream>>>(rowptr, cursor);
  if (use_new)
    k_fill_new<<<(NEDGES+255)/256, 256, 0, stream>>>(srcI, dstI, ea, cursor, srcp, eap24);
  else
    k_fill<<<(NEDGES+255)/256, 256, 0, stream>>>(srcI, dstI, ea, cursor, perm, srcp, eaperm);
  k_selfe<<<NLAYER, EMBD, 0, stream>>>(eb1, ew2, eb2, selfe);

  // ---- weight prep ----
  k_wc<<<(NLAYER*EMBD*2*EMBD)/256, 256, 0, stream>>>(ew2, mw1, wc);
  k_pack<<<(192*EMBD+255)/256, 256, 0, stream>>>(iw1, XDIM, iw1, XDIM, 192, EMBD, Bi1);
  k_pack<<<(EMBD*EMBD+255)/256, 256, 0, stream>>>(iw2, EMBD, iw2, EMBD, EMBD, EMBD, Bi2);
  for (int l=0; l<NLAYER; ++l){
    k_pack<<<(256*256+255)/256, 256, 0, stream>>>(
        wc + (size_t)l*EMBD*2*EMBD, EMBD, mw1 + (size_t)l*EMBD*2*EMBD, 256, 256, 256,
        B1 + (size_t)l*256*256*2);
    k_pack<<<(256*EMBD+255)/256, 256, 0, stream>>>(
        mw2 + (size_t)l*2*EMBD*EMBD, 256, mw2, 256, 256, EMBD,
        B2 + (size_t)l*256*EMBD*2);
  }

  const int gx = (NNODES + 127)/128;

  // ---- input MLP ----
  k_mgemm<128,4,2, true,1,false,false,false,true ,false><<<gx, 512, 0, stream>>>(
      x, nullptr, nullptr, NNODES, XDIM, 192, XDIM, Bi1, ib1, S1, nullptr, EMBD, nullptr);
  k_mgemm<128,4,2, true,0,false,false,false,false,false><<<gx, 512, 0, stream>>>(
      S1, nullptr, nullptr, NNODES, EMBD, EMBD, EMBD, Bi2, ib2, hbuf, nullptr, EMBD, nullptr);

  for (int l=0; l<NLAYER; ++l){
    hipMemsetAsync(stats, 0, 2*EMBD*4, stream);
    if (use_new)
      k_edge_mfma<<<1536, 256, 0, stream>>>(
          hbuf, rowptr, srcp, eap24,
          ew1 + (size_t)l*EDIM*EMBD, eb1 + l*EMBD, eb2 + l*EMBD, selfe + l*EMBD,
          S1, base);
    else
      k_edge<<<NNODES/4, 256, 0, stream>>>(
          hbuf, rowptr, perm, srcp, ea, eaperm,
          ew1 + (size_t)l*EDIM*EMBD, eb1 + l*EMBD, eb2 + l*EMBD, selfe + l*EMBD,
          S1, base);
    // t = relu([S1|base] @ [Wc;mw1] + mb1)  -> bf16 [N,256]
    k_mgemm<256,2,4, true,2,false,true ,true ,false,false><<<gx, 512, 0, stream>>>(
        S1, base, nullptr, NNODES, 256, 256, EMBD, B1 + (size_t)l*256*256*2,
        mb1 + l*2*EMBD, nullptr, tbuf, 2*EMBD, nullptr);
    // hh (into S1) = t @ mw2 + mb2, fused BN stats
    k_mgemm<128,4,2, false,0,true ,false,false,false,true ><<<gx, 512, 0, stream>>>(
        nullptr, nullptr, tbuf, NNODES, 256, 256, 2*EMBD, B2 + (size_t)l*256*EMBD*2,
        mb2 + l*EMBD, S1, nullptr, EMBD, stats);
    float* outp = (l == NLAYER-1) ? (float*)d_out : hbuf;
    k_bn<<<(NNODES*(EMBD/4)+255)/256, 256, 0, stream>>>(
        S1, stats, gamma + l*EMBD, beta + l*EMBD, outp, (l < NLAYER-1) ? 1 : 0);
  }
}